// Round 4
// baseline (451.099 us; speedup 1.0000x reference)
//
#include <hip/hip_runtime.h>
#include <math.h>

// Sizes: N=2000, M=32, H=64, EMB=32, F=32, T=12, B=4, HOR=12, K=2, DILS=(1,2)

// ---------------- K1: node MLP -> q, ek, nh2 (= e@w_nhp + b_nhp + b_in); also xT ----
__global__ __launch_bounds__(256) void k_embed(
    const float* __restrict__ nf, const float* __restrict__ inputs,
    const float* __restrict__ w3, const float* __restrict__ b3,
    const float* __restrict__ w4, const float* __restrict__ b4,
    const float* __restrict__ w5, const float* __restrict__ b5,
    const float* __restrict__ wq, const float* __restrict__ wk,
    const float* __restrict__ wn, const float* __restrict__ bn,
    const float* __restrict__ b_in,
    float* __restrict__ qo, float* __restrict__ eko, float* __restrict__ nho,
    float* __restrict__ xT)
{
    const int tid = threadIdx.x;
    if (tid < 192) {                                   // xT transpose: 500*192 = 96000
        const int id = blockIdx.x * 192 + tid;
        const int t = id / 8000, rem = id % 8000;
        const int b = rem / 2000, n2 = rem % 2000;
        xT[n2 * 48 + b * 12 + t] = inputs[id];
    }
    const int lane = tid & 63;
    const int n = blockIdx.x * 4 + (tid >> 6);

    float nfv = 0.f;
    if (lane < 32) nfv = nf[n * 32 + lane];

    float e1 = b3[lane];
#pragma unroll
    for (int f = 0; f < 32; ++f)
        e1 = fmaf(__shfl(nfv, f), w3[f * 64 + lane], e1);
    e1 = fmaxf(e1, 0.f);

    float e2 = b4[lane];
#pragma unroll
    for (int f = 0; f < 64; ++f)
        e2 = fmaf(__shfl(e1, f), w4[f * 64 + lane], e2);
    e2 = fmaxf(e2, 0.f);

    const int c = lane & 31;
    float ev = b5[c];
#pragma unroll
    for (int f = 0; f < 64; ++f)
        ev = fmaf(__shfl(e2, f), w5[f * 32 + c], ev);

    float qv = 0.f, ekv = 0.f, nhv = bn[lane] + b_in[lane];
#pragma unroll
    for (int f = 0; f < 32; ++f) {
        float e = __shfl(ev, f);
        qv  = fmaf(e, wq[f * 64 + lane], qv);
        ekv = fmaf(e, wk[f * 64 + lane], ekv);
        nhv = fmaf(e, wn[f * 64 + lane], nhv);
    }
    qo [n * 64 + lane] = qv;
    eko[n * 64 + lane] = ekv;
    nho[n * 64 + lane] = nhv;
}

// ---------------- K2: attention scores + softmax -> w_adj ----------
__global__ __launch_bounds__(256) void k_scores(
    const float* __restrict__ q, const float* __restrict__ ek,
    const int* __restrict__ nidx, float* __restrict__ wadj)
{
    const int tid = threadIdx.x;
    const int m = tid & 31;
    const int n = blockIdx.x * 8 + (tid >> 5);
    const int j = nidx[n * 32 + m];
    const float4* qr = (const float4*)(q + n * 64);
    const float4* er = (const float4*)(ek + j * 64);
    float s = 0.f;
#pragma unroll
    for (int u = 0; u < 16; ++u) {
        float4 a = qr[u], b = er[u];
        s = fmaf(a.x, b.x, s); s = fmaf(a.y, b.y, s);
        s = fmaf(a.z, b.z, s); s = fmaf(a.w, b.w, s);
    }
    s *= 0.125f;
    float mx = s;
#pragma unroll
    for (int d = 16; d >= 1; d >>= 1) mx = fmaxf(mx, __shfl_xor(mx, d));
    const float ex = expf(s - mx);
    float sum = ex;
#pragma unroll
    for (int d = 16; d >= 1; d >>= 1) sum += __shfl_xor(sum, d);
    wadj[n * 32 + m] = ex / sum;
}

// ---------------- K3: ax[n][bt] = sum_m w[n,m] * x[bt, j_m];  pack xa = {x_self, ax} ----
__global__ __launch_bounds__(256) void k_ax(
    const float* __restrict__ xT, const int* __restrict__ nidx,
    const float* __restrict__ wadj, float2* __restrict__ xa)
{
    const int lane = threadIdx.x & 63, wave = threadIdx.x >> 6;
    const int n = blockIdx.x * 4 + wave;
    int j = 0; float w = 0.f;
    if (lane < 32) { j = nidx[n * 32 + lane]; w = wadj[n * 32 + lane]; }
    const bool act = lane < 48;
    float ax = 0.f;
#pragma unroll
    for (int m = 0; m < 32; ++m) {
        const int jm = __shfl(j, m);
        const float wm = __shfl(w, m);
        const float xv = act ? xT[jm * 48 + lane] : 0.f;
        ax = fmaf(wm, xv, ax);
    }
    if (act) xa[n * 48 + lane] = make_float2(xT[n * 48 + lane], ax);
}

// ---------------- K3b: base1[n] = nh2[n]@Ws1 + (A nh2)[n]@Wn1 + b1 ; block 500: vecs ----
__global__ __launch_bounds__(256) void k_prep(
    const float* __restrict__ nh2, const int* __restrict__ nidx,
    const float* __restrict__ wadj,
    const float* __restrict__ sws, const float* __restrict__ sbs,
    const float* __restrict__ swn, const float* __restrict__ sbn,
    const float* __restrict__ w_in,
    float* __restrict__ base1, float* __restrict__ vecs)
{
    const int tid = threadIdx.x;
    const int lane = tid & 63, wave = tid >> 6;
    if (blockIdx.x == 500) {                      // s1v = w_in@Ws1, n1v = w_in@Wn1
        if (wave == 0) {
            const float wv = w_in[lane];
            float s1 = 0.f, n1 = 0.f;
#pragma unroll
            for (int k = 0; k < 64; ++k) {
                const float wkk = __shfl(wv, k);
                s1 = fmaf(wkk, sws[k * 64 + lane], s1);
                n1 = fmaf(wkk, swn[k * 64 + lane], n1);
            }
            vecs[lane] = s1; vecs[64 + lane] = n1;
        }
        return;
    }
    __shared__ float2 sw1[4096];
    __shared__ float2 sv1[4][64];
    for (int u = tid; u < 4096; u += 256)
        sw1[u] = make_float2(sws[u], swn[u]);
    __syncthreads();
    const int n = blockIdx.x * 4 + wave;
    int jv = 0; float wv = 0.f;
    if (lane < 32) { jv = nidx[n * 32 + lane]; wv = wadj[n * 32 + lane]; }
    const float self = nh2[n * 64 + lane];
    float anh = 0.f;
#pragma unroll
    for (int m = 0; m < 32; ++m) {
        const int jm = __shfl(jv, m);
        const float wm = __shfl(wv, m);
        anh = fmaf(wm, nh2[jm * 64 + lane], anh);
    }
    sv1[wave][lane] = make_float2(self, anh);
    float acc = sbs[lane] + sbn[lane];
#pragma unroll
    for (int k = 0; k < 64; ++k) {
        const float2 sa = sv1[wave][k];            // broadcast
        const float2 w2 = sw1[k * 64 + lane];
        acc = fmaf(sa.x, w2.x, fmaf(sa.y, w2.y, acc));
    }
    base1[n * 64 + lane] = acc;
}

// ---------------- K4: fused SAGE layer 2 (recompute h1 from scalars) -> mid ----------
__global__ __launch_bounds__(512, 4) void k_sage2(
    const float* __restrict__ base1, const float2* __restrict__ xa,
    const float* __restrict__ vecs,
    const int* __restrict__ nidx, const float* __restrict__ wadj,
    const float* __restrict__ sws, const float* __restrict__ sbs,
    const float* __restrict__ swn, const float* __restrict__ sbn,
    float* __restrict__ mid)
{
    __shared__ float2 sw2[4096];                  // {Ws2,Wn2}[k*64+h], 32 KB
    __shared__ float2 sv[48][64];                 // {h1self, agg}[bt][k], 24 KB
    __shared__ int2 jwl[32];                      // {j, bits(w)}
    const int tid = threadIdx.x, lane = tid & 63, wave = tid >> 6;
    const int n = blockIdx.x;
    if (tid < 32)
        jwl[tid] = make_int2(nidx[n * 32 + tid], __float_as_int(wadj[n * 32 + tid]));
    for (int u = tid; u < 4096; u += 512)
        sw2[u] = make_float2(sws[4096 + u], swn[4096 + u]);
    __syncthreads();

    const float s1 = vecs[lane], n1 = vecs[64 + lane];
    const float bs = base1[n * 64 + lane];
    const float b2 = sbs[64 + lane] + sbn[64 + lane];
    const int bt0 = wave * 6;

    float agg[6] = {0.f, 0.f, 0.f, 0.f, 0.f, 0.f};
#pragma unroll 8
    for (int m = 0; m < 32; ++m) {
        const int2 jw = jwl[m];
        const int j = jw.x;
        const float w = __int_as_float(jw.y);
        const float bj = base1[j * 64 + lane];
        const float2* xr = xa + j * 48 + bt0;
#pragma unroll
        for (int r = 0; r < 6; ++r) {
            const float2 v = xr[r];
            const float t = fmaf(v.x, s1, fmaf(v.y, n1, bj));
            agg[r] = fmaf(w, fmaxf(t, 0.f), agg[r]);
        }
    }
#pragma unroll
    for (int r = 0; r < 6; ++r) {
        const float2 v = xa[n * 48 + bt0 + r];
        const float h1s = fmaxf(fmaf(v.x, s1, fmaf(v.y, n1, bs)), 0.f);
        sv[bt0 + r][lane] = make_float2(h1s, agg[r]);
    }
    float acc[6];
#pragma unroll
    for (int r = 0; r < 6; ++r) acc[r] = b2;
#pragma unroll
    for (int k = 0; k < 64; ++k) {
        const float2 w2 = sw2[k * 64 + lane];
#pragma unroll
        for (int r = 0; r < 6; ++r) {
            const float2 ha = sv[bt0 + r][k];
            acc[r] = fmaf(ha.x, w2.x, fmaf(ha.y, w2.y, acc[r]));
        }
    }
#pragma unroll
    for (int r = 0; r < 6; ++r)
        mid[((bt0 + r) * 2000 + n) * 64 + lane] = fmaxf(acc[r], 0.f);
}

// ---------------- K5: TCN cone-pruned + head ----------
// Only ht[:,:,11] is consumed downstream -> compute the causal dependency cone:
// load x1 at t=5..11 (7 slots); s1 (D=1) valid t=6..11; s2 (D=1) valid t=7,9,11;
// s3 (D=2) valid t=9,11; s4 (D=2) valid t=11. One wave = 9 seqs x 7 slots
// (lane = s*7 + j, t = 5+j). Channel vectors in registers; the causal shift is
// applied AFTER the contraction via one __shfl(z0, lane-delta) per output ch.
// Weights are wave-uniform -> scalarized s_load (SMEM pipe, SGPR fma operand):
// no LDS weight staging, no barriers. Rolled o-loop writes go through a
// per-thread XOR-swizzled LDS row (dynamic VGPR indexing is not allowed).
__device__ __forceinline__ void conv_pass(const float* xv, const float* __restrict__ wrow0,
    const float* __restrict__ bias, int delta, float* ybuf, int ybase, int swz, int lane)
{
    for (int o = 0; o < 64; ++o) {
        const float* __restrict__ w = wrow0 + o * 128;   // [i*2 + k], i=0..63
        float z0a=0.f, z0b=0.f, z0c=0.f, z0d=0.f;
        float z1a=0.f, z1b=0.f, z1c=0.f, z1d=0.f;
#pragma unroll
        for (int q = 0; q < 16; ++q) {
            z0a = fmaf(w[8*q+0], xv[4*q+0], z0a);
            z1a = fmaf(w[8*q+1], xv[4*q+0], z1a);
            z0b = fmaf(w[8*q+2], xv[4*q+1], z0b);
            z1b = fmaf(w[8*q+3], xv[4*q+1], z1b);
            z0c = fmaf(w[8*q+4], xv[4*q+2], z0c);
            z1c = fmaf(w[8*q+5], xv[4*q+2], z1c);
            z0d = fmaf(w[8*q+6], xv[4*q+3], z0d);
            z1d = fmaf(w[8*q+7], xv[4*q+3], z1d);
        }
        const float z0 = (z0a + z0b) + (z0c + z0d);      // tap k=0: x[t-D]
        const float z1 = (z1a + z1b) + (z1c + z1d);      // tap k=1: x[t]
        const float z0s = __shfl(z0, lane - delta);      // shift across t-slots
        const float y = fmaxf(bias[o] + z0s + z1, 0.f);
        ybuf[ybase + (o ^ swz)] = y;
    }
}

__global__ __launch_bounds__(64, 3) void k_tcn(
    const float* __restrict__ mid,
    const float* __restrict__ tw1, const float* __restrict__ tb1,
    const float* __restrict__ tw2, const float* __restrict__ tb2,
    const float* __restrict__ wgate, const float* __restrict__ bgate,
    const float* __restrict__ wout, const float* __restrict__ bout,
    float* __restrict__ outp)
{
    __shared__ float ybuf[64 * 64];                      // 16 KB, per-thread row
    const int lane = threadIdx.x;
    const int s = lane / 7;                              // 0..9 (s==9: idle lane)
    const int j = lane - s * 7;                          // 0..6
    const int t = 5 + j;
    int seq = blockIdx.x * 9 + s;
    const bool valid = (s < 9) && (seq < 8000);
    if (!valid) seq = 0;
    const int b = seq / 2000, n = seq - b * 2000;
    const int swz = lane & 31;
    const int ybase = lane * 64;

    // load x1[t=5+j]
    float x1[64];
    {
        const float4* src = (const float4*)(mid + ((long)((b * 12 + t) * 2000 + n)) * 64);
#pragma unroll
        for (int q = 0; q < 16; ++q) {
            const float4 v = src[q];
            x1[4*q+0] = v.x; x1[4*q+1] = v.y; x1[4*q+2] = v.z; x1[4*q+3] = v.w;
        }
    }

    // stage 1: layer0 conv1 (D=1)
    conv_pass(x1, tw1, tb1, 1, ybuf, ybase, swz, lane);
    float y1[64];
#pragma unroll
    for (int i = 0; i < 64; ++i) y1[i] = ybuf[ybase + (i ^ swz)];

    // stage 2: layer0 conv2 (D=1), then x2 = relu(y2 + x1)
    conv_pass(y1, tw2, tb2, 1, ybuf, ybase, swz, lane);
    float x2[64];
#pragma unroll
    for (int i = 0; i < 64; ++i)
        x2[i] = fmaxf(ybuf[ybase + (i ^ swz)] + x1[i], 0.f);

    // stage 3: layer1 conv1 (D=2)
    conv_pass(x2, tw1 + 8192, tb1 + 64, 2, ybuf, ybase, swz, lane);
    float y3[64];
#pragma unroll
    for (int i = 0; i < 64; ++i) y3[i] = ybuf[ybase + (i ^ swz)];

    // stage 4: layer1 conv2 (D=2), then ht = relu(y4 + x2)
    conv_pass(y3, tw2 + 8192, tb2 + 64, 2, ybuf, ybase, swz, lane);
    float ht[64];
#pragma unroll
    for (int i = 0; i < 64; ++i)
        ht[i] = fmaxf(ybuf[ybase + (i ^ swz)] + x2[i], 0.f);

    // epilogue: only t=11 (j==6) lanes produce output
    if (valid && j == 6) {
        float hs[64];
        const float4* hsrc = (const float4*)(mid + ((long)((b * 12 + 11) * 2000 + n)) * 64);
#pragma unroll
        for (int q = 0; q < 16; ++q) {
            const float4 v = hsrc[q];
            hs[4*q+0] = v.x; hs[4*q+1] = v.y; hs[4*q+2] = v.z; hs[4*q+3] = v.w;
        }
        float p = 0.f;
#pragma unroll
        for (int o = 0; o < 64; ++o) p = fmaf(ht[o], wgate[o], p);
        const float g = 1.f / (1.f + expf(-(p + bgate[0])));
        float acc[12];
#pragma unroll
        for (int h = 0; h < 12; ++h) acc[h] = bout[h];
        for (int o = 0; o < 64; ++o) {
            const float fo = g * ht[o] + (1.f - g) * hs[o];
            const float* __restrict__ wr = wout + o * 12;
#pragma unroll
            for (int h = 0; h < 12; ++h) acc[h] = fmaf(fo, wr[h], acc[h]);
        }
#pragma unroll
        for (int h = 0; h < 12; ++h) outp[h * 8000 + seq] = acc[h];
    }
}

extern "C" void kernel_launch(void* const* d_in, const int* in_sizes, int n_in,
                              void* d_out, int out_size, void* d_ws, size_t ws_size,
                              hipStream_t stream) {
    const float* inputs     = (const float*)d_in[0];
    const float* node_feas  = (const float*)d_in[1];
    const int*   node_index = (const int*)  d_in[2];
    const float* w_fc3 = (const float*)d_in[3];
    const float* b_fc3 = (const float*)d_in[4];
    const float* w_fc4 = (const float*)d_in[5];
    const float* b_fc4 = (const float*)d_in[6];
    const float* w_fc5 = (const float*)d_in[7];
    const float* b_fc5 = (const float*)d_in[8];
    const float* w_nhp = (const float*)d_in[9];
    const float* b_nhp = (const float*)d_in[10];
    const float* w_q   = (const float*)d_in[11];
    const float* w_k   = (const float*)d_in[12];
    const float* w_in  = (const float*)d_in[13];
    const float* b_in  = (const float*)d_in[14];
    const float* sws   = (const float*)d_in[15];
    const float* sbs   = (const float*)d_in[16];
    const float* swn   = (const float*)d_in[17];
    const float* sbn   = (const float*)d_in[18];
    const float* tw1   = (const float*)d_in[19];
    const float* tb1   = (const float*)d_in[20];
    const float* tw2   = (const float*)d_in[21];
    const float* tb2   = (const float*)d_in[22];
    const float* wgate = (const float*)d_in[23];
    const float* bgate = (const float*)d_in[24];
    const float* wout  = (const float*)d_in[25];
    const float* bout  = (const float*)d_in[26];

    float* out  = (float*)d_out;           // (12,4,2000)        96000
    float* mid  = out + 96000;             // (4,12,2000,64)     6144000
    float* wadj = mid + 6144000;           // (2000,32)          64000

    float*  q     = (float*)d_ws;          // 128000
    float*  ek    = q     + 128000;        // 128000
    float*  nh2   = ek    + 128000;        // 128000 (includes b_nhp + b_in)
    float*  base1 = nh2   + 128000;        // 128000
    float*  xT    = base1 + 128000;        // 96000   [n][bt]
    float2* xa    = (float2*)(xT + 96000); // 96000 float2 {x, ax}
    float*  vecs  = xT + 96000 + 192000;   // 128 {s1v, n1v}

    k_embed<<<500, 256, 0, stream>>>(node_feas, inputs, w_fc3, b_fc3, w_fc4, b_fc4,
                                     w_fc5, b_fc5, w_q, w_k, w_nhp, b_nhp, b_in,
                                     q, ek, nh2, xT);
    k_scores<<<250, 256, 0, stream>>>(q, ek, node_index, wadj);
    k_ax<<<500, 256, 0, stream>>>(xT, node_index, wadj, xa);
    k_prep<<<501, 256, 0, stream>>>(nh2, node_index, wadj, sws, sbs, swn, sbn,
                                    w_in, base1, vecs);
    k_sage2<<<2000, 512, 0, stream>>>(base1, xa, vecs, node_index, wadj,
                                      sws, sbs, swn, sbn, mid);
    k_tcn<<<889, 64, 0, stream>>>(mid, tw1, tb1, tw2, tb2,
                                  wgate, bgate, wout, bout, out);
}

// Round 5
// 200.060 us; speedup vs baseline: 2.2548x; 2.2548x over previous
//
#include <hip/hip_runtime.h>
#include <math.h>

// Sizes: N=2000, M=32, H=64, EMB=32, F=32, T=12, B=4, HOR=12, K=2, DILS=(1,2)

// ---------------- K1: node MLP -> q, ek, nh2 (= e@w_nhp + b_nhp + b_in); also xT ----
__global__ __launch_bounds__(256) void k_embed(
    const float* __restrict__ nf, const float* __restrict__ inputs,
    const float* __restrict__ w3, const float* __restrict__ b3,
    const float* __restrict__ w4, const float* __restrict__ b4,
    const float* __restrict__ w5, const float* __restrict__ b5,
    const float* __restrict__ wq, const float* __restrict__ wk,
    const float* __restrict__ wn, const float* __restrict__ bn,
    const float* __restrict__ b_in,
    float* __restrict__ qo, float* __restrict__ eko, float* __restrict__ nho,
    float* __restrict__ xT)
{
    const int tid = threadIdx.x;
    if (tid < 192) {                                   // xT transpose: 500*192 = 96000
        const int id = blockIdx.x * 192 + tid;
        const int t = id / 8000, rem = id % 8000;
        const int b = rem / 2000, n2 = rem % 2000;
        xT[n2 * 48 + b * 12 + t] = inputs[id];
    }
    const int lane = tid & 63;
    const int n = blockIdx.x * 4 + (tid >> 6);

    float nfv = 0.f;
    if (lane < 32) nfv = nf[n * 32 + lane];

    float e1 = b3[lane];
#pragma unroll
    for (int f = 0; f < 32; ++f)
        e1 = fmaf(__shfl(nfv, f), w3[f * 64 + lane], e1);
    e1 = fmaxf(e1, 0.f);

    float e2 = b4[lane];
#pragma unroll
    for (int f = 0; f < 64; ++f)
        e2 = fmaf(__shfl(e1, f), w4[f * 64 + lane], e2);
    e2 = fmaxf(e2, 0.f);

    const int c = lane & 31;
    float ev = b5[c];
#pragma unroll
    for (int f = 0; f < 64; ++f)
        ev = fmaf(__shfl(e2, f), w5[f * 32 + c], ev);

    float qv = 0.f, ekv = 0.f, nhv = bn[lane] + b_in[lane];
#pragma unroll
    for (int f = 0; f < 32; ++f) {
        float e = __shfl(ev, f);
        qv  = fmaf(e, wq[f * 64 + lane], qv);
        ekv = fmaf(e, wk[f * 64 + lane], ekv);
        nhv = fmaf(e, wn[f * 64 + lane], nhv);
    }
    qo [n * 64 + lane] = qv;
    eko[n * 64 + lane] = ekv;
    nho[n * 64 + lane] = nhv;
}

// ---------------- K2: attention scores + softmax -> w_adj ----------
__global__ __launch_bounds__(256) void k_scores(
    const float* __restrict__ q, const float* __restrict__ ek,
    const int* __restrict__ nidx, float* __restrict__ wadj)
{
    const int tid = threadIdx.x;
    const int m = tid & 31;
    const int n = blockIdx.x * 8 + (tid >> 5);
    const int j = nidx[n * 32 + m];
    const float4* qr = (const float4*)(q + n * 64);
    const float4* er = (const float4*)(ek + j * 64);
    float s = 0.f;
#pragma unroll
    for (int u = 0; u < 16; ++u) {
        float4 a = qr[u], b = er[u];
        s = fmaf(a.x, b.x, s); s = fmaf(a.y, b.y, s);
        s = fmaf(a.z, b.z, s); s = fmaf(a.w, b.w, s);
    }
    s *= 0.125f;
    float mx = s;
#pragma unroll
    for (int d = 16; d >= 1; d >>= 1) mx = fmaxf(mx, __shfl_xor(mx, d));
    const float ex = expf(s - mx);
    float sum = ex;
#pragma unroll
    for (int d = 16; d >= 1; d >>= 1) sum += __shfl_xor(sum, d);
    wadj[n * 32 + m] = ex / sum;
}

// ---------------- K3: ax[n][bt] = sum_m w[n,m] * x[bt, j_m];  pack xa = {x_self, ax} ----
__global__ __launch_bounds__(256) void k_ax(
    const float* __restrict__ xT, const int* __restrict__ nidx,
    const float* __restrict__ wadj, float2* __restrict__ xa)
{
    const int lane = threadIdx.x & 63, wave = threadIdx.x >> 6;
    const int n = blockIdx.x * 4 + wave;
    int j = 0; float w = 0.f;
    if (lane < 32) { j = nidx[n * 32 + lane]; w = wadj[n * 32 + lane]; }
    const bool act = lane < 48;
    float ax = 0.f;
#pragma unroll
    for (int m = 0; m < 32; ++m) {
        const int jm = __shfl(j, m);
        const float wm = __shfl(w, m);
        const float xv = act ? xT[jm * 48 + lane] : 0.f;
        ax = fmaf(wm, xv, ax);
    }
    if (act) xa[n * 48 + lane] = make_float2(xT[n * 48 + lane], ax);
}

// ---------------- K3b: base1[n] = nh2[n]@Ws1 + (A nh2)[n]@Wn1 + b1 ; block 500: vecs ----
__global__ __launch_bounds__(256) void k_prep(
    const float* __restrict__ nh2, const int* __restrict__ nidx,
    const float* __restrict__ wadj,
    const float* __restrict__ sws, const float* __restrict__ sbs,
    const float* __restrict__ swn, const float* __restrict__ sbn,
    const float* __restrict__ w_in,
    float* __restrict__ base1, float* __restrict__ vecs)
{
    const int tid = threadIdx.x;
    const int lane = tid & 63, wave = tid >> 6;
    if (blockIdx.x == 500) {                      // s1v = w_in@Ws1, n1v = w_in@Wn1
        if (wave == 0) {
            const float wv = w_in[lane];
            float s1 = 0.f, n1 = 0.f;
#pragma unroll
            for (int k = 0; k < 64; ++k) {
                const float wkk = __shfl(wv, k);
                s1 = fmaf(wkk, sws[k * 64 + lane], s1);
                n1 = fmaf(wkk, swn[k * 64 + lane], n1);
            }
            vecs[lane] = s1; vecs[64 + lane] = n1;
        }
        return;
    }
    __shared__ float2 sw1[4096];
    __shared__ float2 sv1[4][64];
    for (int u = tid; u < 4096; u += 256)
        sw1[u] = make_float2(sws[u], swn[u]);
    __syncthreads();
    const int n = blockIdx.x * 4 + wave;
    int jv = 0; float wv = 0.f;
    if (lane < 32) { jv = nidx[n * 32 + lane]; wv = wadj[n * 32 + lane]; }
    const float self = nh2[n * 64 + lane];
    float anh = 0.f;
#pragma unroll
    for (int m = 0; m < 32; ++m) {
        const int jm = __shfl(jv, m);
        const float wm = __shfl(wv, m);
        anh = fmaf(wm, nh2[jm * 64 + lane], anh);
    }
    sv1[wave][lane] = make_float2(self, anh);
    float acc = sbs[lane] + sbn[lane];
#pragma unroll
    for (int k = 0; k < 64; ++k) {
        const float2 sa = sv1[wave][k];            // broadcast
        const float2 w2 = sw1[k * 64 + lane];
        acc = fmaf(sa.x, w2.x, fmaf(sa.y, w2.y, acc));
    }
    base1[n * 64 + lane] = acc;
}

// ---------------- K4: fused SAGE layer 2 (recompute h1 from scalars) -> mid ----------
__global__ __launch_bounds__(512, 4) void k_sage2(
    const float* __restrict__ base1, const float2* __restrict__ xa,
    const float* __restrict__ vecs,
    const int* __restrict__ nidx, const float* __restrict__ wadj,
    const float* __restrict__ sws, const float* __restrict__ sbs,
    const float* __restrict__ swn, const float* __restrict__ sbn,
    float* __restrict__ mid)
{
    __shared__ float2 sw2[4096];                  // {Ws2,Wn2}[k*64+h], 32 KB
    __shared__ float2 sv[48][64];                 // {h1self, agg}[bt][k], 24 KB
    __shared__ int2 jwl[32];                      // {j, bits(w)}
    const int tid = threadIdx.x, lane = tid & 63, wave = tid >> 6;
    const int n = blockIdx.x;
    if (tid < 32)
        jwl[tid] = make_int2(nidx[n * 32 + tid], __float_as_int(wadj[n * 32 + tid]));
    for (int u = tid; u < 4096; u += 512)
        sw2[u] = make_float2(sws[4096 + u], swn[4096 + u]);
    __syncthreads();

    const float s1 = vecs[lane], n1 = vecs[64 + lane];
    const float bs = base1[n * 64 + lane];
    const float b2 = sbs[64 + lane] + sbn[64 + lane];
    const int bt0 = wave * 6;

    float agg[6] = {0.f, 0.f, 0.f, 0.f, 0.f, 0.f};
#pragma unroll 8
    for (int m = 0; m < 32; ++m) {
        const int2 jw = jwl[m];
        const int j = jw.x;
        const float w = __int_as_float(jw.y);
        const float bj = base1[j * 64 + lane];
        const float2* xr = xa + j * 48 + bt0;
#pragma unroll
        for (int r = 0; r < 6; ++r) {
            const float2 v = xr[r];
            const float t = fmaf(v.x, s1, fmaf(v.y, n1, bj));
            agg[r] = fmaf(w, fmaxf(t, 0.f), agg[r]);
        }
    }
#pragma unroll
    for (int r = 0; r < 6; ++r) {
        const float2 v = xa[n * 48 + bt0 + r];
        const float h1s = fmaxf(fmaf(v.x, s1, fmaf(v.y, n1, bs)), 0.f);
        sv[bt0 + r][lane] = make_float2(h1s, agg[r]);
    }
    float acc[6];
#pragma unroll
    for (int r = 0; r < 6; ++r) acc[r] = b2;
#pragma unroll
    for (int k = 0; k < 64; ++k) {
        const float2 w2 = sw2[k * 64 + lane];
#pragma unroll
        for (int r = 0; r < 6; ++r) {
            const float2 ha = sv[bt0 + r][k];
            acc[r] = fmaf(ha.x, w2.x, fmaf(ha.y, w2.y, acc[r]));
        }
    }
#pragma unroll
    for (int r = 0; r < 6; ++r)
        mid[((bt0 + r) * 2000 + n) * 64 + lane] = fmaxf(acc[r], 0.f);
}

// ---------------- K5a: transpose TCN weights to [conv][i][o]{k0,k1} ----------
__global__ __launch_bounds__(256) void k_wT(
    const float* __restrict__ tw1, const float* __restrict__ tw2,
    float2* __restrict__ wt)
{
    const int id = blockIdx.x * 256 + threadIdx.x;    // 16384 total
    const int c = id >> 12;                           // 0..3
    const int r = id & 4095;
    const int i = r >> 6, o = r & 63;
    const float* src = (c == 0) ? tw1 : (c == 1) ? tw2
                     : (c == 2) ? tw1 + 8192 : tw2 + 8192;
    wt[id] = make_float2(src[o * 128 + i * 2], src[o * 128 + i * 2 + 1]);
}

// ---------------- K5: TCN cone-pruned, lane=channel, zero LDS ----------
// Only ht[:,:,11] is consumed. Causal cone: x1 t=5..11 (7), y1 t=6..11 (6),
// x2 t=7,9,11 (3), y3 t=9,11 (2), ht t=11 (1). All slots are NAMED registers
// (one float per lane=channel). Cross-channel broadcast via __shfl with
// fully-unrolled compile-time source lane -> v_readlane (no LDS, no barrier).
// Weights read coalesced from the [i][o]{k0,k1} transposed copy (L1-hot).
__global__ __launch_bounds__(256) void k_tcn(
    const float* __restrict__ mid, const float2* __restrict__ wt,
    const float* __restrict__ tb1, const float* __restrict__ tb2,
    const float* __restrict__ wgate, const float* __restrict__ bgate,
    const float* __restrict__ wout, const float* __restrict__ bout,
    float* __restrict__ outp)
{
    const int lane = threadIdx.x & 63;
    const int seq = blockIdx.x * 4 + (threadIdx.x >> 6);   // 2000 blocks * 4 waves
    const int b = seq / 2000, n = seq - b * 2000;
    const float* xbase = mid + ((long)(b * 12) * 2000 + n) * 64 + lane;

    // x1 slots t=5..11
    float x10 = xbase[ 5 * 128000], x11 = xbase[ 6 * 128000], x12 = xbase[ 7 * 128000],
          x13 = xbase[ 8 * 128000], x14 = xbase[ 9 * 128000], x15 = xbase[10 * 128000],
          x16 = xbase[11 * 128000];

    // ---- stage 1: layer0 conv1 (D=1): y1[t]=relu(b + sum_i w0*x[t-1]+w1*x[t]), t=6..11
    const float bs1 = tb1[lane];
    float y10 = bs1, y11 = bs1, y12 = bs1, y13 = bs1, y14 = bs1, y15 = bs1;
#pragma unroll
    for (int i = 0; i < 64; ++i) {
        const float2 w = wt[i * 64 + lane];
        const float b0 = __shfl(x10, i), b1 = __shfl(x11, i), b2 = __shfl(x12, i),
                    b3 = __shfl(x13, i), b4 = __shfl(x14, i), b5 = __shfl(x15, i),
                    b6 = __shfl(x16, i);
        y10 = fmaf(w.x, b0, fmaf(w.y, b1, y10));
        y11 = fmaf(w.x, b1, fmaf(w.y, b2, y11));
        y12 = fmaf(w.x, b2, fmaf(w.y, b3, y12));
        y13 = fmaf(w.x, b3, fmaf(w.y, b4, y13));
        y14 = fmaf(w.x, b4, fmaf(w.y, b5, y14));
        y15 = fmaf(w.x, b5, fmaf(w.y, b6, y15));
    }
    y10 = fmaxf(y10, 0.f); y11 = fmaxf(y11, 0.f); y12 = fmaxf(y12, 0.f);
    y13 = fmaxf(y13, 0.f); y14 = fmaxf(y14, 0.f); y15 = fmaxf(y15, 0.f);

    // ---- stage 2: layer0 conv2 (D=1) at t=7,9,11; x2[t]=relu(relu(y2)+x1[t])
    const float bs2 = tb2[lane];
    float a0 = bs2, a1 = bs2, a2 = bs2;
#pragma unroll
    for (int i = 0; i < 64; ++i) {
        const float2 w = wt[4096 + i * 64 + lane];
        const float c0 = __shfl(y10, i), c1 = __shfl(y11, i), c2 = __shfl(y12, i),
                    c3 = __shfl(y13, i), c4 = __shfl(y14, i), c5 = __shfl(y15, i);
        a0 = fmaf(w.x, c0, fmaf(w.y, c1, a0));   // t=7 : y1@6, y1@7
        a1 = fmaf(w.x, c2, fmaf(w.y, c3, a1));   // t=9 : y1@8, y1@9
        a2 = fmaf(w.x, c4, fmaf(w.y, c5, a2));   // t=11: y1@10,y1@11
    }
    const float x20 = fmaxf(fmaxf(a0, 0.f) + x12, 0.f);   // t=7
    const float x21 = fmaxf(fmaxf(a1, 0.f) + x14, 0.f);   // t=9
    const float x22 = fmaxf(fmaxf(a2, 0.f) + x16, 0.f);   // t=11

    // ---- stage 3: layer1 conv1 (D=2) at t=9,11
    const float bs3 = tb1[64 + lane];
    float d0 = bs3, d1 = bs3;
#pragma unroll
    for (int i = 0; i < 64; ++i) {
        const float2 w = wt[8192 + i * 64 + lane];
        const float e0 = __shfl(x20, i), e1 = __shfl(x21, i), e2 = __shfl(x22, i);
        d0 = fmaf(w.x, e0, fmaf(w.y, e1, d0));   // t=9 : x2@7, x2@9
        d1 = fmaf(w.x, e1, fmaf(w.y, e2, d1));   // t=11: x2@9, x2@11
    }
    const float y30 = fmaxf(d0, 0.f), y31 = fmaxf(d1, 0.f);

    // ---- stage 4: layer1 conv2 (D=2) at t=11; ht = relu(relu(y4)+x2@11)
    const float bs4 = tb2[64 + lane];
    float f0 = bs4;
#pragma unroll
    for (int i = 0; i < 64; ++i) {
        const float2 w = wt[12288 + i * 64 + lane];
        const float g0 = __shfl(y30, i), g1 = __shfl(y31, i);
        f0 = fmaf(w.x, g0, fmaf(w.y, g1, f0));
    }
    const float ht = fmaxf(fmaxf(f0, 0.f) + x22, 0.f);

    // ---- epilogue: gate + fuse + w_out, all 64 lanes cooperate
    const float hs = xbase[11 * 128000];                 // mid[:, -1]
    float p = ht * wgate[lane];
#pragma unroll
    for (int d = 1; d < 64; d <<= 1) p += __shfl_xor(p, d);
    const float g = 1.f / (1.f + expf(-(p + bgate[0])));
    const float fo = g * ht + (1.f - g) * hs;

    float acc[12];
    {
        const float4* wr = (const float4*)(wout + lane * 12);   // 48B: 16-aligned
        const float4 wa = wr[0], wb = wr[1], wc = wr[2];
        acc[0] = fo * wa.x; acc[1] = fo * wa.y; acc[2]  = fo * wa.z; acc[3]  = fo * wa.w;
        acc[4] = fo * wb.x; acc[5] = fo * wb.y; acc[6]  = fo * wb.z; acc[7]  = fo * wb.w;
        acc[8] = fo * wc.x; acc[9] = fo * wc.y; acc[10] = fo * wc.z; acc[11] = fo * wc.w;
    }
#pragma unroll
    for (int d = 1; d < 64; d <<= 1) {
#pragma unroll
        for (int h = 0; h < 12; ++h) acc[h] += __shfl_xor(acc[h], d);
    }
    if (lane == 0) {
#pragma unroll
        for (int h = 0; h < 12; ++h) outp[h * 8000 + seq] = acc[h] + bout[h];
    }
}

extern "C" void kernel_launch(void* const* d_in, const int* in_sizes, int n_in,
                              void* d_out, int out_size, void* d_ws, size_t ws_size,
                              hipStream_t stream) {
    const float* inputs     = (const float*)d_in[0];
    const float* node_feas  = (const float*)d_in[1];
    const int*   node_index = (const int*)  d_in[2];
    const float* w_fc3 = (const float*)d_in[3];
    const float* b_fc3 = (const float*)d_in[4];
    const float* w_fc4 = (const float*)d_in[5];
    const float* b_fc4 = (const float*)d_in[6];
    const float* w_fc5 = (const float*)d_in[7];
    const float* b_fc5 = (const float*)d_in[8];
    const float* w_nhp = (const float*)d_in[9];
    const float* b_nhp = (const float*)d_in[10];
    const float* w_q   = (const float*)d_in[11];
    const float* w_k   = (const float*)d_in[12];
    const float* w_in  = (const float*)d_in[13];
    const float* b_in  = (const float*)d_in[14];
    const float* sws   = (const float*)d_in[15];
    const float* sbs   = (const float*)d_in[16];
    const float* swn   = (const float*)d_in[17];
    const float* sbn   = (const float*)d_in[18];
    const float* tw1   = (const float*)d_in[19];
    const float* tb1   = (const float*)d_in[20];
    const float* tw2   = (const float*)d_in[21];
    const float* tb2   = (const float*)d_in[22];
    const float* wgate = (const float*)d_in[23];
    const float* bgate = (const float*)d_in[24];
    const float* wout  = (const float*)d_in[25];
    const float* bout  = (const float*)d_in[26];

    float* out  = (float*)d_out;           // (12,4,2000)        96000
    float* mid  = out + 96000;             // (4,12,2000,64)     6144000
    float* wadj = mid + 6144000;           // (2000,32)          64000

    float*  q     = (float*)d_ws;          // 128000
    float*  ek    = q     + 128000;        // 128000
    float*  nh2   = ek    + 128000;        // 128000 (includes b_nhp + b_in)
    float*  base1 = nh2   + 128000;        // 128000
    float*  xT    = base1 + 128000;        // 96000   [n][bt]
    float2* xa    = (float2*)(xT + 96000); // 96000 float2 {x, ax}
    float*  vecs  = xT + 96000 + 192000;   // 128 {s1v, n1v}
    float2* wt    = (float2*)(vecs + 128); // 16384 float2 (transposed TCN weights)

    k_embed<<<500, 256, 0, stream>>>(node_feas, inputs, w_fc3, b_fc3, w_fc4, b_fc4,
                                     w_fc5, b_fc5, w_q, w_k, w_nhp, b_nhp, b_in,
                                     q, ek, nh2, xT);
    k_wT<<<64, 256, 0, stream>>>(tw1, tw2, wt);
    k_scores<<<250, 256, 0, stream>>>(q, ek, node_index, wadj);
    k_ax<<<500, 256, 0, stream>>>(xT, node_index, wadj, xa);
    k_prep<<<501, 256, 0, stream>>>(nh2, node_index, wadj, sws, sbs, swn, sbn,
                                    w_in, base1, vecs);
    k_sage2<<<2000, 512, 0, stream>>>(base1, xa, vecs, node_index, wadj,
                                      sws, sbs, swn, sbn, mid);
    k_tcn<<<2000, 256, 0, stream>>>(mid, wt, tb1, tb2,
                                    wgate, bgate, wout, bout, out);
}

// Round 6
// 150.935 us; speedup vs baseline: 2.9887x; 1.3255x over previous
//
#include <hip/hip_runtime.h>
#include <math.h>

// Sizes: N=2000, M=32, H=64, EMB=32, F=32, T=12, B=4, HOR=12, K=2, DILS=(1,2)

// ---------------- K1: node MLP -> q, ek, nh2; also xT and TCN weight transpose ----
__global__ __launch_bounds__(256) void k_embed(
    const float* __restrict__ nf, const float* __restrict__ inputs,
    const float* __restrict__ w3, const float* __restrict__ b3,
    const float* __restrict__ w4, const float* __restrict__ b4,
    const float* __restrict__ w5, const float* __restrict__ b5,
    const float* __restrict__ wq, const float* __restrict__ wk,
    const float* __restrict__ wn, const float* __restrict__ bn,
    const float* __restrict__ b_in,
    const float* __restrict__ tw1, const float* __restrict__ tw2,
    float2* __restrict__ wtx,
    float* __restrict__ qo, float* __restrict__ eko, float* __restrict__ nho,
    float* __restrict__ xT)
{
    const int tid = threadIdx.x;
    if (tid < 192) {                                   // xT transpose: 500*192 = 96000
        const int id = blockIdx.x * 192 + tid;
        const int t = id / 8000, rem = id % 8000;
        const int b = rem / 2000, n2 = rem % 2000;
        xT[n2 * 48 + b * 12 + t] = inputs[id];
    }
    if (blockIdx.x < 64) {                             // TCN weights -> [conv][i][o]{k0,k1}
        const int id = blockIdx.x * 256 + tid;
        const int c = id >> 12, rr = id & 4095;
        const int i = rr >> 6, o = rr & 63;
        const float* src = (c == 0) ? tw1 : (c == 1) ? tw2
                         : (c == 2) ? tw1 + 8192 : tw2 + 8192;
        wtx[id] = make_float2(src[o * 128 + i * 2], src[o * 128 + i * 2 + 1]);
    }
    const int lane = tid & 63;
    const int n = blockIdx.x * 4 + (tid >> 6);

    float nfv = 0.f;
    if (lane < 32) nfv = nf[n * 32 + lane];

    float e1 = b3[lane];
#pragma unroll
    for (int f = 0; f < 32; ++f)
        e1 = fmaf(__shfl(nfv, f), w3[f * 64 + lane], e1);
    e1 = fmaxf(e1, 0.f);

    float e2 = b4[lane];
#pragma unroll
    for (int f = 0; f < 64; ++f)
        e2 = fmaf(__shfl(e1, f), w4[f * 64 + lane], e2);
    e2 = fmaxf(e2, 0.f);

    const int c = lane & 31;
    float ev = b5[c];
#pragma unroll
    for (int f = 0; f < 64; ++f)
        ev = fmaf(__shfl(e2, f), w5[f * 32 + c], ev);

    float qv = 0.f, ekv = 0.f, nhv = bn[lane] + b_in[lane];
#pragma unroll
    for (int f = 0; f < 32; ++f) {
        float e = __shfl(ev, f);
        qv  = fmaf(e, wq[f * 64 + lane], qv);
        ekv = fmaf(e, wk[f * 64 + lane], ekv);
        nhv = fmaf(e, wn[f * 64 + lane], nhv);
    }
    qo [n * 64 + lane] = qv;
    eko[n * 64 + lane] = ekv;
    nho[n * 64 + lane] = nhv;
}

// ---------------- K2: attention scores + softmax -> w_adj ----------
__global__ __launch_bounds__(256) void k_scores(
    const float* __restrict__ q, const float* __restrict__ ek,
    const int* __restrict__ nidx, float* __restrict__ wadj)
{
    const int tid = threadIdx.x;
    const int m = tid & 31;
    const int n = blockIdx.x * 8 + (tid >> 5);
    const int j = nidx[n * 32 + m];
    const float4* qr = (const float4*)(q + n * 64);
    const float4* er = (const float4*)(ek + j * 64);
    float s = 0.f;
#pragma unroll
    for (int u = 0; u < 16; ++u) {
        float4 a = qr[u], b = er[u];
        s = fmaf(a.x, b.x, s); s = fmaf(a.y, b.y, s);
        s = fmaf(a.z, b.z, s); s = fmaf(a.w, b.w, s);
    }
    s *= 0.125f;
    float mx = s;
#pragma unroll
    for (int d = 16; d >= 1; d >>= 1) mx = fmaxf(mx, __shfl_xor(mx, d));
    const float ex = expf(s - mx);
    float sum = ex;
#pragma unroll
    for (int d = 16; d >= 1; d >>= 1) sum += __shfl_xor(sum, d);
    wadj[n * 32 + m] = ex / sum;
}

// ---------------- K3: ax[n][bt] = sum_m w[n,m] * x[bt, j_m];  pack xa = {x_self, ax} ----
__global__ __launch_bounds__(256) void k_ax(
    const float* __restrict__ xT, const int* __restrict__ nidx,
    const float* __restrict__ wadj, float2* __restrict__ xa)
{
    const int lane = threadIdx.x & 63, wave = threadIdx.x >> 6;
    const int n = blockIdx.x * 4 + wave;
    int j = 0; float w = 0.f;
    if (lane < 32) { j = nidx[n * 32 + lane]; w = wadj[n * 32 + lane]; }
    const bool act = lane < 48;
    float ax = 0.f;
#pragma unroll
    for (int m = 0; m < 32; ++m) {
        const int jm = __shfl(j, m);
        const float wm = __shfl(w, m);
        const float xv = act ? xT[jm * 48 + lane] : 0.f;
        ax = fmaf(wm, xv, ax);
    }
    if (act) xa[n * 48 + lane] = make_float2(xT[n * 48 + lane], ax);
}

// ---------------- K3b: base1[n] = nh2[n]@Ws1 + (A nh2)[n]@Wn1 + b1 ; block 500: vecs ----
__global__ __launch_bounds__(256) void k_prep(
    const float* __restrict__ nh2, const int* __restrict__ nidx,
    const float* __restrict__ wadj,
    const float* __restrict__ sws, const float* __restrict__ sbs,
    const float* __restrict__ swn, const float* __restrict__ sbn,
    const float* __restrict__ w_in,
    float* __restrict__ base1, float* __restrict__ vecs)
{
    const int tid = threadIdx.x;
    const int lane = tid & 63, wave = tid >> 6;
    if (blockIdx.x == 500) {                      // s1v = w_in@Ws1, n1v = w_in@Wn1
        if (wave == 0) {
            const float wv = w_in[lane];
            float s1 = 0.f, n1 = 0.f;
#pragma unroll
            for (int k = 0; k < 64; ++k) {
                const float wkk = __shfl(wv, k);
                s1 = fmaf(wkk, sws[k * 64 + lane], s1);
                n1 = fmaf(wkk, swn[k * 64 + lane], n1);
            }
            vecs[lane] = s1; vecs[64 + lane] = n1;
        }
        return;
    }
    __shared__ float2 sw1[4096];
    __shared__ float2 sv1[4][64];
    for (int u = tid; u < 4096; u += 256)
        sw1[u] = make_float2(sws[u], swn[u]);
    __syncthreads();
    const int n = blockIdx.x * 4 + wave;
    int jv = 0; float wv = 0.f;
    if (lane < 32) { jv = nidx[n * 32 + lane]; wv = wadj[n * 32 + lane]; }
    const float self = nh2[n * 64 + lane];
    float anh = 0.f;
#pragma unroll
    for (int m = 0; m < 32; ++m) {
        const int jm = __shfl(jv, m);
        const float wm = __shfl(wv, m);
        anh = fmaf(wm, nh2[jm * 64 + lane], anh);
    }
    sv1[wave][lane] = make_float2(self, anh);
    float acc = sbs[lane] + sbn[lane];
#pragma unroll
    for (int k = 0; k < 64; ++k) {
        const float2 sa = sv1[wave][k];            // broadcast
        const float2 w2 = sw1[k * 64 + lane];
        acc = fmaf(sa.x, w2.x, fmaf(sa.y, w2.y, acc));
    }
    base1[n * 64 + lane] = acc;
}

// ---------------- K4: fused SAGE layer 2 (recompute h1 from scalars) -> mid ----------
__global__ __launch_bounds__(512, 4) void k_sage2(
    const float* __restrict__ base1, const float2* __restrict__ xa,
    const float* __restrict__ vecs,
    const int* __restrict__ nidx, const float* __restrict__ wadj,
    const float* __restrict__ sws, const float* __restrict__ sbs,
    const float* __restrict__ swn, const float* __restrict__ sbn,
    float* __restrict__ mid)
{
    __shared__ float2 sw2[4096];                  // {Ws2,Wn2}[k*64+h], 32 KB
    __shared__ float2 sv[48][64];                 // {h1self, agg}[bt][k], 24 KB
    __shared__ int2 jwl[32];                      // {j, bits(w)}
    const int tid = threadIdx.x, lane = tid & 63, wave = tid >> 6;
    const int n = blockIdx.x;
    if (tid < 32)
        jwl[tid] = make_int2(nidx[n * 32 + tid], __float_as_int(wadj[n * 32 + tid]));
    for (int u = tid; u < 4096; u += 512)
        sw2[u] = make_float2(sws[4096 + u], swn[4096 + u]);
    __syncthreads();

    const float s1 = vecs[lane], n1 = vecs[64 + lane];
    const float bs = base1[n * 64 + lane];
    const float b2 = sbs[64 + lane] + sbn[64 + lane];
    const int bt0 = wave * 6;

    float agg[6] = {0.f, 0.f, 0.f, 0.f, 0.f, 0.f};
#pragma unroll 8
    for (int m = 0; m < 32; ++m) {
        const int2 jw = jwl[m];
        const int j = jw.x;
        const float w = __int_as_float(jw.y);
        const float bj = base1[j * 64 + lane];
        const float2* xr = xa + j * 48 + bt0;
#pragma unroll
        for (int r = 0; r < 6; ++r) {
            const float2 v = xr[r];
            const float t = fmaf(v.x, s1, fmaf(v.y, n1, bj));
            agg[r] = fmaf(w, fmaxf(t, 0.f), agg[r]);
        }
    }
#pragma unroll
    for (int r = 0; r < 6; ++r) {
        const float2 v = xa[n * 48 + bt0 + r];
        const float h1s = fmaxf(fmaf(v.x, s1, fmaf(v.y, n1, bs)), 0.f);
        sv[bt0 + r][lane] = make_float2(h1s, agg[r]);
    }
    float acc[6];
#pragma unroll
    for (int r = 0; r < 6; ++r) acc[r] = b2;
#pragma unroll
    for (int k = 0; k < 64; ++k) {
        const float2 w2 = sw2[k * 64 + lane];
#pragma unroll
        for (int r = 0; r < 6; ++r) {
            const float2 ha = sv[bt0 + r][k];
            acc[r] = fmaf(ha.x, w2.x, fmaf(ha.y, w2.y, acc[r]));
        }
    }
#pragma unroll
    for (int r = 0; r < 6; ++r)
        mid[((bt0 + r) * 2000 + n) * 64 + lane] = fmaxf(acc[r], 0.f);
}

// ---------------- K5: TCN cone-pruned, lane=channel, 4 seqs/wave ----------
// Cone: only ht[:,:,11] is consumed. Per wave (4 seqs): stage1 y1@t=6..11 from
// wave-uniform global loads of mid (s_load path, no LDS); stages 2-4 broadcast
// intermediates via per-wave LDS float4 uniform-address reads (conflict-free);
// weights from transposed wt, one coalesced float2 load feeds 4 seqs.
__global__ __launch_bounds__(256, 2) void k_tcn(
    const float* __restrict__ mid, const float2* __restrict__ wt,
    const float* __restrict__ tb1, const float* __restrict__ tb2,
    const float* __restrict__ wgate, const float* __restrict__ bgate,
    const float* __restrict__ wout, const float* __restrict__ bout,
    float* __restrict__ outp)
{
    __shared__ __align__(16) float buf[4][4][6][68];     // [wave][seq][slot][ch+pad]
    const int tid = threadIdx.x, lane = tid & 63;
    const int wv = __builtin_amdgcn_readfirstlane(tid >> 6);
    const int sb = blockIdx.x * 16 + wv * 4;             // seqs sb..sb+3 (same b)
    const int b = sb / 2000, n0 = sb - b * 2000;
    const float* __restrict__ xb = mid + ((long)(b * 12) * 2000 + n0) * 64;

    // residuals r[s][u] at t=7,9,11 (per-lane coalesced); r[s][2] doubles as h_s
    float r[4][3];
#pragma unroll
    for (int s = 0; s < 4; ++s) {
        r[s][0] = xb[ 7 * 128000 + s * 64 + lane];
        r[s][1] = xb[ 9 * 128000 + s * 64 + lane];
        r[s][2] = xb[11 * 128000 + s * 64 + lane];
    }

    // ---- stage 1: y1[s][j], t=6+j, j=0..5; x slots t=5+u via uniform loads
    const float bs1 = tb1[lane];
    float y1[4][6];
#pragma unroll
    for (int s = 0; s < 4; ++s)
#pragma unroll
        for (int j = 0; j < 6; ++j) y1[s][j] = bs1;
#pragma unroll 2
    for (int ig = 0; ig < 16; ++ig) {
        float2 w0 = wt[(ig * 4 + 0) * 64 + lane];
        float2 w1 = wt[(ig * 4 + 1) * 64 + lane];
        float2 w2 = wt[(ig * 4 + 2) * 64 + lane];
        float2 w3 = wt[(ig * 4 + 3) * 64 + lane];
#pragma unroll
        for (int s = 0; s < 4; ++s) {
            float4 xu[7];
#pragma unroll
            for (int u = 0; u < 7; ++u)
                xu[u] = *(const float4*)(xb + (5 + u) * 128000 + s * 64 + ig * 4);
#pragma unroll
            for (int j = 0; j < 6; ++j) {
                float acc = y1[s][j];
                acc = fmaf(w0.x, xu[j].x, acc); acc = fmaf(w0.y, xu[j + 1].x, acc);
                acc = fmaf(w1.x, xu[j].y, acc); acc = fmaf(w1.y, xu[j + 1].y, acc);
                acc = fmaf(w2.x, xu[j].z, acc); acc = fmaf(w2.y, xu[j + 1].z, acc);
                acc = fmaf(w3.x, xu[j].w, acc); acc = fmaf(w3.y, xu[j + 1].w, acc);
                y1[s][j] = acc;
            }
        }
    }
#pragma unroll
    for (int s = 0; s < 4; ++s)
#pragma unroll
        for (int j = 0; j < 6; ++j)
            buf[wv][s][j][lane] = fmaxf(y1[s][j], 0.f);
    __syncthreads();

    // ---- stage 2: a[s][v] at t=7,9,11 from y1 (LDS broadcast)
    const float bs2 = tb2[lane];
    float a[4][3];
#pragma unroll
    for (int s = 0; s < 4; ++s) { a[s][0] = bs2; a[s][1] = bs2; a[s][2] = bs2; }
#pragma unroll 2
    for (int ig = 0; ig < 16; ++ig) {
        float2 w0 = wt[4096 + (ig * 4 + 0) * 64 + lane];
        float2 w1 = wt[4096 + (ig * 4 + 1) * 64 + lane];
        float2 w2 = wt[4096 + (ig * 4 + 2) * 64 + lane];
        float2 w3 = wt[4096 + (ig * 4 + 3) * 64 + lane];
#pragma unroll
        for (int s = 0; s < 4; ++s) {
            float4 yv[6];
#pragma unroll
            for (int j = 0; j < 6; ++j)
                yv[j] = *(const float4*)&buf[wv][s][j][ig * 4];
#pragma unroll
            for (int v = 0; v < 3; ++v) {
                float acc = a[s][v];
                acc = fmaf(w0.x, yv[2*v].x, acc); acc = fmaf(w0.y, yv[2*v+1].x, acc);
                acc = fmaf(w1.x, yv[2*v].y, acc); acc = fmaf(w1.y, yv[2*v+1].y, acc);
                acc = fmaf(w2.x, yv[2*v].z, acc); acc = fmaf(w2.y, yv[2*v+1].z, acc);
                acc = fmaf(w3.x, yv[2*v].w, acc); acc = fmaf(w3.y, yv[2*v+1].w, acc);
                a[s][v] = acc;
            }
        }
    }
    float x22[4];
#pragma unroll
    for (int s = 0; s < 4; ++s) {
        const float x20 = fmaxf(fmaxf(a[s][0], 0.f) + r[s][0], 0.f);  // t=7
        const float x21 = fmaxf(fmaxf(a[s][1], 0.f) + r[s][1], 0.f);  // t=9
        x22[s]          = fmaxf(fmaxf(a[s][2], 0.f) + r[s][2], 0.f);  // t=11
        buf[wv][s][0][lane] = x20;
        buf[wv][s][1][lane] = x21;
        buf[wv][s][2][lane] = x22[s];
    }
    __syncthreads();

    // ---- stage 3: d[s][v] at t=9,11 (D=2) from x2 slots 0..2
    const float bs3 = tb1[64 + lane];
    float d[4][2];
#pragma unroll
    for (int s = 0; s < 4; ++s) { d[s][0] = bs3; d[s][1] = bs3; }
#pragma unroll 2
    for (int ig = 0; ig < 16; ++ig) {
        float2 w0 = wt[8192 + (ig * 4 + 0) * 64 + lane];
        float2 w1 = wt[8192 + (ig * 4 + 1) * 64 + lane];
        float2 w2 = wt[8192 + (ig * 4 + 2) * 64 + lane];
        float2 w3 = wt[8192 + (ig * 4 + 3) * 64 + lane];
#pragma unroll
        for (int s = 0; s < 4; ++s) {
            float4 x0 = *(const float4*)&buf[wv][s][0][ig * 4];
            float4 x1 = *(const float4*)&buf[wv][s][1][ig * 4];
            float4 x2 = *(const float4*)&buf[wv][s][2][ig * 4];
            float acc0 = d[s][0], acc1 = d[s][1];
            acc0 = fmaf(w0.x, x0.x, acc0); acc0 = fmaf(w0.y, x1.x, acc0);
            acc0 = fmaf(w1.x, x0.y, acc0); acc0 = fmaf(w1.y, x1.y, acc0);
            acc0 = fmaf(w2.x, x0.z, acc0); acc0 = fmaf(w2.y, x1.z, acc0);
            acc0 = fmaf(w3.x, x0.w, acc0); acc0 = fmaf(w3.y, x1.w, acc0);
            acc1 = fmaf(w0.x, x1.x, acc1); acc1 = fmaf(w0.y, x2.x, acc1);
            acc1 = fmaf(w1.x, x1.y, acc1); acc1 = fmaf(w1.y, x2.y, acc1);
            acc1 = fmaf(w2.x, x1.z, acc1); acc1 = fmaf(w2.y, x2.z, acc1);
            acc1 = fmaf(w3.x, x1.w, acc1); acc1 = fmaf(w3.y, x2.w, acc1);
            d[s][0] = acc0; d[s][1] = acc1;
        }
    }
#pragma unroll
    for (int s = 0; s < 4; ++s) {
        buf[wv][s][4][lane] = fmaxf(d[s][0], 0.f);   // y3@9
        buf[wv][s][5][lane] = fmaxf(d[s][1], 0.f);   // y3@11
    }
    __syncthreads();

    // ---- stage 4: f[s] at t=11 (D=2) from y3 slots 4,5; ht = relu(relu(f)+x2@11)
    const float bs4 = tb2[64 + lane];
    float f[4] = {bs4, bs4, bs4, bs4};
#pragma unroll 2
    for (int ig = 0; ig < 16; ++ig) {
        float2 w0 = wt[12288 + (ig * 4 + 0) * 64 + lane];
        float2 w1 = wt[12288 + (ig * 4 + 1) * 64 + lane];
        float2 w2 = wt[12288 + (ig * 4 + 2) * 64 + lane];
        float2 w3 = wt[12288 + (ig * 4 + 3) * 64 + lane];
#pragma unroll
        for (int s = 0; s < 4; ++s) {
            float4 g0 = *(const float4*)&buf[wv][s][4][ig * 4];
            float4 g1 = *(const float4*)&buf[wv][s][5][ig * 4];
            float acc = f[s];
            acc = fmaf(w0.x, g0.x, acc); acc = fmaf(w0.y, g1.x, acc);
            acc = fmaf(w1.x, g0.y, acc); acc = fmaf(w1.y, g1.y, acc);
            acc = fmaf(w2.x, g0.z, acc); acc = fmaf(w2.y, g1.z, acc);
            acc = fmaf(w3.x, g0.w, acc); acc = fmaf(w3.y, g1.w, acc);
            f[s] = acc;
        }
    }

    // ---- epilogue: gate + fuse; fo -> LDS; 48 lanes do the 12-wide head GEMV
    const float wg = wgate[lane];
#pragma unroll
    for (int s = 0; s < 4; ++s) {
        const float ht = fmaxf(fmaxf(f[s], 0.f) + x22[s], 0.f);
        float p = ht * wg;
#pragma unroll
        for (int dd = 1; dd < 64; dd <<= 1) p += __shfl_xor(p, dd);
        const float g = 1.f / (1.f + expf(-(p + bgate[0])));
        buf[wv][s][5][lane] = g * ht + (1.f - g) * r[s][2];
    }
    __syncthreads();
    if (lane < 48) {
        const int s = lane / 12, h = lane - s * 12;
        float acc = bout[h];
#pragma unroll 4
        for (int ig = 0; ig < 16; ++ig) {
            const float4 f4 = *(const float4*)&buf[wv][s][5][ig * 4];
            acc = fmaf(f4.x, wout[(ig * 4 + 0) * 12 + h], acc);
            acc = fmaf(f4.y, wout[(ig * 4 + 1) * 12 + h], acc);
            acc = fmaf(f4.z, wout[(ig * 4 + 2) * 12 + h], acc);
            acc = fmaf(f4.w, wout[(ig * 4 + 3) * 12 + h], acc);
        }
        outp[h * 8000 + sb + s] = acc;
    }
}

extern "C" void kernel_launch(void* const* d_in, const int* in_sizes, int n_in,
                              void* d_out, int out_size, void* d_ws, size_t ws_size,
                              hipStream_t stream) {
    const float* inputs     = (const float*)d_in[0];
    const float* node_feas  = (const float*)d_in[1];
    const int*   node_index = (const int*)  d_in[2];
    const float* w_fc3 = (const float*)d_in[3];
    const float* b_fc3 = (const float*)d_in[4];
    const float* w_fc4 = (const float*)d_in[5];
    const float* b_fc4 = (const float*)d_in[6];
    const float* w_fc5 = (const float*)d_in[7];
    const float* b_fc5 = (const float*)d_in[8];
    const float* w_nhp = (const float*)d_in[9];
    const float* b_nhp = (const float*)d_in[10];
    const float* w_q   = (const float*)d_in[11];
    const float* w_k   = (const float*)d_in[12];
    const float* w_in  = (const float*)d_in[13];
    const float* b_in  = (const float*)d_in[14];
    const float* sws   = (const float*)d_in[15];
    const float* sbs   = (const float*)d_in[16];
    const float* swn   = (const float*)d_in[17];
    const float* sbn   = (const float*)d_in[18];
    const float* tw1   = (const float*)d_in[19];
    const float* tb1   = (const float*)d_in[20];
    const float* tw2   = (const float*)d_in[21];
    const float* tb2   = (const float*)d_in[22];
    const float* wgate = (const float*)d_in[23];
    const float* bgate = (const float*)d_in[24];
    const float* wout  = (const float*)d_in[25];
    const float* bout  = (const float*)d_in[26];

    float* out  = (float*)d_out;           // (12,4,2000)        96000
    float* mid  = out + 96000;             // (4,12,2000,64)     6144000
    float* wadj = mid + 6144000;           // (2000,32)          64000

    float*  q     = (float*)d_ws;          // 128000
    float*  ek    = q     + 128000;        // 128000
    float*  nh2   = ek    + 128000;        // 128000 (includes b_nhp + b_in)
    float*  base1 = nh2   + 128000;        // 128000
    float*  xT    = base1 + 128000;        // 96000   [n][bt]
    float2* xa    = (float2*)(xT + 96000); // 96000 float2 {x, ax}
    float*  vecs  = xT + 96000 + 192000;   // 128 {s1v, n1v}
    float2* wt    = (float2*)(vecs + 128); // 16384 float2 (transposed TCN weights)

    k_embed<<<500, 256, 0, stream>>>(node_feas, inputs, w_fc3, b_fc3, w_fc4, b_fc4,
                                     w_fc5, b_fc5, w_q, w_k, w_nhp, b_nhp, b_in,
                                     tw1, tw2, wt,
                                     q, ek, nh2, xT);
    k_scores<<<250, 256, 0, stream>>>(q, ek, node_index, wadj);
    k_ax<<<500, 256, 0, stream>>>(xT, node_index, wadj, xa);
    k_prep<<<501, 256, 0, stream>>>(nh2, node_index, wadj, sws, sbs, swn, sbn,
                                    w_in, base1, vecs);
    k_sage2<<<2000, 512, 0, stream>>>(base1, xa, vecs, node_index, wadj,
                                      sws, sbs, swn, sbn, mid);
    k_tcn<<<500, 256, 0, stream>>>(mid, wt, tb1, tb2,
                                   wgate, bgate, wout, bout, out);
}

// Round 7
// 126.187 us; speedup vs baseline: 3.5748x; 1.1961x over previous
//
#include <hip/hip_runtime.h>
#include <math.h>

// Sizes: N=2000, M=32, H=64, EMB=32, F=32, T=12, B=4, HOR=12, K=2, DILS=(1,2)

// ---------------- K1: node MLP -> q, ek, nh2; also xT, TCN wT, SAGE wpack ----
__global__ __launch_bounds__(256) void k_embed(
    const float* __restrict__ nf, const float* __restrict__ inputs,
    const float* __restrict__ w3, const float* __restrict__ b3,
    const float* __restrict__ w4, const float* __restrict__ b4,
    const float* __restrict__ w5, const float* __restrict__ b5,
    const float* __restrict__ wq, const float* __restrict__ wk,
    const float* __restrict__ wn, const float* __restrict__ bn,
    const float* __restrict__ b_in,
    const float* __restrict__ tw1, const float* __restrict__ tw2,
    const float* __restrict__ sws, const float* __restrict__ swn,
    float2* __restrict__ wtx, float4* __restrict__ wsg,
    float* __restrict__ qo, float* __restrict__ eko, float* __restrict__ nho,
    float* __restrict__ xT)
{
    const int tid = threadIdx.x;
    if (tid < 192) {                                   // xT transpose: 500*192 = 96000
        const int id = blockIdx.x * 192 + tid;
        const int t = id / 8000, rem = id % 8000;
        const int b = rem / 2000, n2 = rem % 2000;
        xT[n2 * 48 + b * 12 + t] = inputs[id];
    }
    if (blockIdx.x < 64) {                             // TCN weights -> [conv][i][o]{k0,k1}
        const int id = blockIdx.x * 256 + tid;
        const int c = id >> 12, rr = id & 4095;
        const int i = rr >> 6, o = rr & 63;
        const float* src = (c == 0) ? tw1 : (c == 1) ? tw2
                         : (c == 2) ? tw1 + 8192 : tw2 + 8192;
        wtx[id] = make_float2(src[o * 128 + i * 2], src[o * 128 + i * 2 + 1]);
    } else if (blockIdx.x < 80) {                      // SAGE weights -> [l][k2][h] float4
        const int id = (blockIdx.x - 64) * 256 + tid;  // 0..4095
        const int l = id >> 11, rr = id & 2047;
        const int k2 = rr >> 6, h = rr & 63;
        const float* S = sws + l * 4096;
        const float* Nn = swn + l * 4096;
        wsg[id] = make_float4(S[(2 * k2) * 64 + h],     Nn[(2 * k2) * 64 + h],
                              S[(2 * k2 + 1) * 64 + h], Nn[(2 * k2 + 1) * 64 + h]);
    }
    const int lane = tid & 63;
    const int n = blockIdx.x * 4 + (tid >> 6);

    float nfv = 0.f;
    if (lane < 32) nfv = nf[n * 32 + lane];

    float e1 = b3[lane];
#pragma unroll
    for (int f = 0; f < 32; ++f)
        e1 = fmaf(__shfl(nfv, f), w3[f * 64 + lane], e1);
    e1 = fmaxf(e1, 0.f);

    float e2 = b4[lane];
#pragma unroll
    for (int f = 0; f < 64; ++f)
        e2 = fmaf(__shfl(e1, f), w4[f * 64 + lane], e2);
    e2 = fmaxf(e2, 0.f);

    const int c = lane & 31;
    float ev = b5[c];
#pragma unroll
    for (int f = 0; f < 64; ++f)
        ev = fmaf(__shfl(e2, f), w5[f * 32 + c], ev);

    float qv = 0.f, ekv = 0.f, nhv = bn[lane] + b_in[lane];
#pragma unroll
    for (int f = 0; f < 32; ++f) {
        float e = __shfl(ev, f);
        qv  = fmaf(e, wq[f * 64 + lane], qv);
        ekv = fmaf(e, wk[f * 64 + lane], ekv);
        nhv = fmaf(e, wn[f * 64 + lane], nhv);
    }
    qo [n * 64 + lane] = qv;
    eko[n * 64 + lane] = ekv;
    nho[n * 64 + lane] = nhv;
}

// ---------------- K2: fused scores+softmax -> wadj; ax -> xa; base1 (+vecs) ----
// wave per node (4 nodes/block); block 500: vecs = {w_in@Ws1, w_in@Wn1}
__global__ __launch_bounds__(256) void k_front(
    const float* __restrict__ q, const float* __restrict__ ek,
    const float* __restrict__ xT, const float* __restrict__ nh2,
    const int* __restrict__ nidx,
    const float* __restrict__ sws, const float* __restrict__ sbs,
    const float* __restrict__ swn, const float* __restrict__ sbn,
    const float* __restrict__ w_in, const float4* __restrict__ wsg,
    float* __restrict__ wadj, float2* __restrict__ xa,
    float* __restrict__ base1, float* __restrict__ vecs)
{
    const int tid = threadIdx.x;
    const int lane = tid & 63, wave = tid >> 6;
    if (blockIdx.x == 500) {
        if (wave == 0) {
            const float wv = w_in[lane];
            float s1 = 0.f, n1 = 0.f;
#pragma unroll
            for (int k = 0; k < 64; ++k) {
                const float wkk = __shfl(wv, k);
                s1 = fmaf(wkk, sws[k * 64 + lane], s1);
                n1 = fmaf(wkk, swn[k * 64 + lane], n1);
            }
            vecs[lane] = s1; vecs[64 + lane] = n1;
        }
        return;
    }
    __shared__ __align__(16) float2 pair[4][64];
    const int n = blockIdx.x * 4 + wave;

    int j = 0;
    if (lane < 32) j = nidx[n * 32 + lane];
    // scores + softmax (lanes 0..31 carry the 32 neighbors)
    float w;
    {
        const float4* qr = (const float4*)(q + n * 64);
        const float4* er = (const float4*)(ek + j * 64);
        float s = 0.f;
#pragma unroll
        for (int u = 0; u < 16; ++u) {
            const float4 a = qr[u], b = er[u];
            s = fmaf(a.x, b.x, s); s = fmaf(a.y, b.y, s);
            s = fmaf(a.z, b.z, s); s = fmaf(a.w, b.w, s);
        }
        s *= 0.125f;
        float mx = s;
#pragma unroll
        for (int d = 16; d >= 1; d >>= 1) mx = fmaxf(mx, __shfl_xor(mx, d));
        const float ex = expf(s - mx);
        float sum = ex;
#pragma unroll
        for (int d = 16; d >= 1; d >>= 1) sum += __shfl_xor(sum, d);
        w = ex / sum;
        if (lane < 32) wadj[n * 32 + lane] = w;
    }
    // gather: ax over xT (lane<48) and anh over nh2 (all 64 lanes)
    float ax = 0.f, anh = 0.f;
    const bool act = lane < 48;
#pragma unroll 8
    for (int m = 0; m < 32; ++m) {
        const int jm = __shfl(j, m);
        const float wm = __shfl(w, m);
        const float xv = act ? xT[jm * 48 + lane] : 0.f;
        ax  = fmaf(wm, xv, ax);
        anh = fmaf(wm, nh2[jm * 64 + lane], anh);
    }
    if (act) xa[n * 48 + lane] = make_float2(xT[n * 48 + lane], ax);
    pair[wave][lane] = make_float2(nh2[n * 64 + lane], anh);
    __syncthreads();

    // base1 = self@Ws1 + anh@Wn1 + b1  (packed global weights, layer 0)
    float acc = sbs[lane] + sbn[lane];
    const float2* pw = pair[wave];
#pragma unroll
    for (int k2 = 0; k2 < 32; ++k2) {
        const float4 wv = wsg[k2 * 64 + lane];
        const float4 sv = *(const float4*)(pw + k2 * 2);
        acc = fmaf(sv.x, wv.x, acc); acc = fmaf(sv.y, wv.y, acc);
        acc = fmaf(sv.z, wv.z, acc); acc = fmaf(sv.w, wv.w, acc);
    }
    base1[n * 64 + lane] = acc;
}

// ---------------- K3: fused SAGE layer 2 (recompute h1 from scalars) -> mid ----------
// block = node, 8 waves x 6 bt. Barrier-free: j/w via s_load (uniform), weights
// per-lane from packed global (L1-hot), sv via uniform ds_read_b128 (imm offsets).
__global__ __launch_bounds__(512, 8) void k_sage2(
    const float* __restrict__ base1, const float2* __restrict__ xa,
    const float* __restrict__ vecs,
    const int* __restrict__ nidx, const float* __restrict__ wadj,
    const float4* __restrict__ wsg2,
    const float* __restrict__ sbs, const float* __restrict__ sbn,
    float* __restrict__ mid)
{
    __shared__ __align__(16) float2 svp[48][64];        // {h1self, agg}, 24 KB
    const int tid = threadIdx.x, lane = tid & 63;
    const int wave = __builtin_amdgcn_readfirstlane(tid >> 6);
    const int n = blockIdx.x;
    const int bt0 = wave * 6;

    const float s1 = vecs[lane], n1 = vecs[64 + lane];
    const float bs = base1[n * 64 + lane];

    float agg[6] = {0.f, 0.f, 0.f, 0.f, 0.f, 0.f};
#pragma unroll 8
    for (int m = 0; m < 32; ++m) {
        const int j = nidx[n * 32 + m];                 // block-uniform -> s_load
        const float w = wadj[n * 32 + m];               // block-uniform -> s_load
        const float bj = base1[j * 64 + lane];
        const float4* xr = (const float4*)(xa + j * 48 + bt0);
        const float4 p0 = xr[0], p1 = xr[1], p2 = xr[2];
        float t;
        t = fmaf(p0.x, s1, fmaf(p0.y, n1, bj)); agg[0] = fmaf(w, fmaxf(t, 0.f), agg[0]);
        t = fmaf(p0.z, s1, fmaf(p0.w, n1, bj)); agg[1] = fmaf(w, fmaxf(t, 0.f), agg[1]);
        t = fmaf(p1.x, s1, fmaf(p1.y, n1, bj)); agg[2] = fmaf(w, fmaxf(t, 0.f), agg[2]);
        t = fmaf(p1.z, s1, fmaf(p1.w, n1, bj)); agg[3] = fmaf(w, fmaxf(t, 0.f), agg[3]);
        t = fmaf(p2.x, s1, fmaf(p2.y, n1, bj)); agg[4] = fmaf(w, fmaxf(t, 0.f), agg[4]);
        t = fmaf(p2.z, s1, fmaf(p2.w, n1, bj)); agg[5] = fmaf(w, fmaxf(t, 0.f), agg[5]);
    }
    {
        const float4* xs = (const float4*)(xa + n * 48 + bt0);
        const float4 q0 = xs[0], q1 = xs[1], q2 = xs[2];
        svp[bt0 + 0][lane] = make_float2(fmaxf(fmaf(q0.x, s1, fmaf(q0.y, n1, bs)), 0.f), agg[0]);
        svp[bt0 + 1][lane] = make_float2(fmaxf(fmaf(q0.z, s1, fmaf(q0.w, n1, bs)), 0.f), agg[1]);
        svp[bt0 + 2][lane] = make_float2(fmaxf(fmaf(q1.x, s1, fmaf(q1.y, n1, bs)), 0.f), agg[2]);
        svp[bt0 + 3][lane] = make_float2(fmaxf(fmaf(q1.z, s1, fmaf(q1.w, n1, bs)), 0.f), agg[3]);
        svp[bt0 + 4][lane] = make_float2(fmaxf(fmaf(q2.x, s1, fmaf(q2.y, n1, bs)), 0.f), agg[4]);
        svp[bt0 + 5][lane] = make_float2(fmaxf(fmaf(q2.z, s1, fmaf(q2.w, n1, bs)), 0.f), agg[5]);
    }
    // no barrier: each wave reads only its own 6 rows (intra-wave LDS dep)

    const float b2 = sbs[64 + lane] + sbn[64 + lane];
    float acc[6] = {b2, b2, b2, b2, b2, b2};
    const float4* wp = wsg2 + lane;
    const float2* s0 = svp[bt0];
#pragma unroll
    for (int k2 = 0; k2 < 32; ++k2) {
        const float4 w4 = wp[k2 * 64];                  // per-lane global, L1-hot
        const float4 v0 = *(const float4*)(s0 + 0 * 64 + k2 * 2);
        const float4 v1 = *(const float4*)(s0 + 1 * 64 + k2 * 2);
        const float4 v2 = *(const float4*)(s0 + 2 * 64 + k2 * 2);
        const float4 v3 = *(const float4*)(s0 + 3 * 64 + k2 * 2);
        const float4 v4 = *(const float4*)(s0 + 4 * 64 + k2 * 2);
        const float4 v5 = *(const float4*)(s0 + 5 * 64 + k2 * 2);
        acc[0] = fmaf(v0.x, w4.x, fmaf(v0.y, w4.y, fmaf(v0.z, w4.z, fmaf(v0.w, w4.w, acc[0]))));
        acc[1] = fmaf(v1.x, w4.x, fmaf(v1.y, w4.y, fmaf(v1.z, w4.z, fmaf(v1.w, w4.w, acc[1]))));
        acc[2] = fmaf(v2.x, w4.x, fmaf(v2.y, w4.y, fmaf(v2.z, w4.z, fmaf(v2.w, w4.w, acc[2]))));
        acc[3] = fmaf(v3.x, w4.x, fmaf(v3.y, w4.y, fmaf(v3.z, w4.z, fmaf(v3.w, w4.w, acc[3]))));
        acc[4] = fmaf(v4.x, w4.x, fmaf(v4.y, w4.y, fmaf(v4.z, w4.z, fmaf(v4.w, w4.w, acc[4]))));
        acc[5] = fmaf(v5.x, w4.x, fmaf(v5.y, w4.y, fmaf(v5.z, w4.z, fmaf(v5.w, w4.w, acc[5]))));
    }
#pragma unroll
    for (int r = 0; r < 6; ++r)
        mid[((bt0 + r) * 2000 + n) * 64 + lane] = fmaxf(acc[r], 0.f);
}

// ---------------- K4: TCN cone-pruned, lane=channel, 4 seqs/wave ----------
__global__ __launch_bounds__(256, 2) void k_tcn(
    const float* __restrict__ mid, const float2* __restrict__ wt,
    const float* __restrict__ tb1, const float* __restrict__ tb2,
    const float* __restrict__ wgate, const float* __restrict__ bgate,
    const float* __restrict__ wout, const float* __restrict__ bout,
    float* __restrict__ outp)
{
    __shared__ __align__(16) float buf[4][4][6][68];     // [wave][seq][slot][ch+pad]
    const int tid = threadIdx.x, lane = tid & 63;
    const int wv = __builtin_amdgcn_readfirstlane(tid >> 6);
    const int sb = blockIdx.x * 16 + wv * 4;             // seqs sb..sb+3 (same b)
    const int b = sb / 2000, n0 = sb - b * 2000;
    const float* __restrict__ xb = mid + ((long)(b * 12) * 2000 + n0) * 64;

    float r[4][3];
#pragma unroll
    for (int s = 0; s < 4; ++s) {
        r[s][0] = xb[ 7 * 128000 + s * 64 + lane];
        r[s][1] = xb[ 9 * 128000 + s * 64 + lane];
        r[s][2] = xb[11 * 128000 + s * 64 + lane];
    }

    // ---- stage 1
    const float bs1 = tb1[lane];
    float y1[4][6];
#pragma unroll
    for (int s = 0; s < 4; ++s)
#pragma unroll
        for (int j = 0; j < 6; ++j) y1[s][j] = bs1;
#pragma unroll 2
    for (int ig = 0; ig < 16; ++ig) {
        float2 w0 = wt[(ig * 4 + 0) * 64 + lane];
        float2 w1 = wt[(ig * 4 + 1) * 64 + lane];
        float2 w2 = wt[(ig * 4 + 2) * 64 + lane];
        float2 w3 = wt[(ig * 4 + 3) * 64 + lane];
#pragma unroll
        for (int s = 0; s < 4; ++s) {
            float4 xu[7];
#pragma unroll
            for (int u = 0; u < 7; ++u)
                xu[u] = *(const float4*)(xb + (5 + u) * 128000 + s * 64 + ig * 4);
#pragma unroll
            for (int j = 0; j < 6; ++j) {
                float acc = y1[s][j];
                acc = fmaf(w0.x, xu[j].x, acc); acc = fmaf(w0.y, xu[j + 1].x, acc);
                acc = fmaf(w1.x, xu[j].y, acc); acc = fmaf(w1.y, xu[j + 1].y, acc);
                acc = fmaf(w2.x, xu[j].z, acc); acc = fmaf(w2.y, xu[j + 1].z, acc);
                acc = fmaf(w3.x, xu[j].w, acc); acc = fmaf(w3.y, xu[j + 1].w, acc);
                y1[s][j] = acc;
            }
        }
    }
#pragma unroll
    for (int s = 0; s < 4; ++s)
#pragma unroll
        for (int j = 0; j < 6; ++j)
            buf[wv][s][j][lane] = fmaxf(y1[s][j], 0.f);
    __syncthreads();

    // ---- stage 2
    const float bs2 = tb2[lane];
    float a[4][3];
#pragma unroll
    for (int s = 0; s < 4; ++s) { a[s][0] = bs2; a[s][1] = bs2; a[s][2] = bs2; }
#pragma unroll 2
    for (int ig = 0; ig < 16; ++ig) {
        float2 w0 = wt[4096 + (ig * 4 + 0) * 64 + lane];
        float2 w1 = wt[4096 + (ig * 4 + 1) * 64 + lane];
        float2 w2 = wt[4096 + (ig * 4 + 2) * 64 + lane];
        float2 w3 = wt[4096 + (ig * 4 + 3) * 64 + lane];
#pragma unroll
        for (int s = 0; s < 4; ++s) {
            float4 yv[6];
#pragma unroll
            for (int j = 0; j < 6; ++j)
                yv[j] = *(const float4*)&buf[wv][s][j][ig * 4];
#pragma unroll
            for (int v = 0; v < 3; ++v) {
                float acc = a[s][v];
                acc = fmaf(w0.x, yv[2*v].x, acc); acc = fmaf(w0.y, yv[2*v+1].x, acc);
                acc = fmaf(w1.x, yv[2*v].y, acc); acc = fmaf(w1.y, yv[2*v+1].y, acc);
                acc = fmaf(w2.x, yv[2*v].z, acc); acc = fmaf(w2.y, yv[2*v+1].z, acc);
                acc = fmaf(w3.x, yv[2*v].w, acc); acc = fmaf(w3.y, yv[2*v+1].w, acc);
                a[s][v] = acc;
            }
        }
    }
    float x22[4];
#pragma unroll
    for (int s = 0; s < 4; ++s) {
        const float x20 = fmaxf(fmaxf(a[s][0], 0.f) + r[s][0], 0.f);  // t=7
        const float x21 = fmaxf(fmaxf(a[s][1], 0.f) + r[s][1], 0.f);  // t=9
        x22[s]          = fmaxf(fmaxf(a[s][2], 0.f) + r[s][2], 0.f);  // t=11
        buf[wv][s][0][lane] = x20;
        buf[wv][s][1][lane] = x21;
        buf[wv][s][2][lane] = x22[s];
    }
    __syncthreads();

    // ---- stage 3
    const float bs3 = tb1[64 + lane];
    float d[4][2];
#pragma unroll
    for (int s = 0; s < 4; ++s) { d[s][0] = bs3; d[s][1] = bs3; }
#pragma unroll 2
    for (int ig = 0; ig < 16; ++ig) {
        float2 w0 = wt[8192 + (ig * 4 + 0) * 64 + lane];
        float2 w1 = wt[8192 + (ig * 4 + 1) * 64 + lane];
        float2 w2 = wt[8192 + (ig * 4 + 2) * 64 + lane];
        float2 w3 = wt[8192 + (ig * 4 + 3) * 64 + lane];
#pragma unroll
        for (int s = 0; s < 4; ++s) {
            float4 x0 = *(const float4*)&buf[wv][s][0][ig * 4];
            float4 x1 = *(const float4*)&buf[wv][s][1][ig * 4];
            float4 x2 = *(const float4*)&buf[wv][s][2][ig * 4];
            float acc0 = d[s][0], acc1 = d[s][1];
            acc0 = fmaf(w0.x, x0.x, acc0); acc0 = fmaf(w0.y, x1.x, acc0);
            acc0 = fmaf(w1.x, x0.y, acc0); acc0 = fmaf(w1.y, x1.y, acc0);
            acc0 = fmaf(w2.x, x0.z, acc0); acc0 = fmaf(w2.y, x1.z, acc0);
            acc0 = fmaf(w3.x, x0.w, acc0); acc0 = fmaf(w3.y, x1.w, acc0);
            acc1 = fmaf(w0.x, x1.x, acc1); acc1 = fmaf(w0.y, x2.x, acc1);
            acc1 = fmaf(w1.x, x1.y, acc1); acc1 = fmaf(w1.y, x2.y, acc1);
            acc1 = fmaf(w2.x, x1.z, acc1); acc1 = fmaf(w2.y, x2.z, acc1);
            acc1 = fmaf(w3.x, x1.w, acc1); acc1 = fmaf(w3.y, x2.w, acc1);
            d[s][0] = acc0; d[s][1] = acc1;
        }
    }
#pragma unroll
    for (int s = 0; s < 4; ++s) {
        buf[wv][s][4][lane] = fmaxf(d[s][0], 0.f);   // y3@9
        buf[wv][s][5][lane] = fmaxf(d[s][1], 0.f);   // y3@11
    }
    __syncthreads();

    // ---- stage 4
    const float bs4 = tb2[64 + lane];
    float f[4] = {bs4, bs4, bs4, bs4};
#pragma unroll 2
    for (int ig = 0; ig < 16; ++ig) {
        float2 w0 = wt[12288 + (ig * 4 + 0) * 64 + lane];
        float2 w1 = wt[12288 + (ig * 4 + 1) * 64 + lane];
        float2 w2 = wt[12288 + (ig * 4 + 2) * 64 + lane];
        float2 w3 = wt[12288 + (ig * 4 + 3) * 64 + lane];
#pragma unroll
        for (int s = 0; s < 4; ++s) {
            float4 g0 = *(const float4*)&buf[wv][s][4][ig * 4];
            float4 g1 = *(const float4*)&buf[wv][s][5][ig * 4];
            float acc = f[s];
            acc = fmaf(w0.x, g0.x, acc); acc = fmaf(w0.y, g1.x, acc);
            acc = fmaf(w1.x, g0.y, acc); acc = fmaf(w1.y, g1.y, acc);
            acc = fmaf(w2.x, g0.z, acc); acc = fmaf(w2.y, g1.z, acc);
            acc = fmaf(w3.x, g0.w, acc); acc = fmaf(w3.y, g1.w, acc);
            f[s] = acc;
        }
    }

    // ---- epilogue
    const float wg = wgate[lane];
#pragma unroll
    for (int s = 0; s < 4; ++s) {
        const float ht = fmaxf(fmaxf(f[s], 0.f) + x22[s], 0.f);
        float p = ht * wg;
#pragma unroll
        for (int dd = 1; dd < 64; dd <<= 1) p += __shfl_xor(p, dd);
        const float g = 1.f / (1.f + expf(-(p + bgate[0])));
        buf[wv][s][5][lane] = g * ht + (1.f - g) * r[s][2];
    }
    __syncthreads();
    if (lane < 48) {
        const int s = lane / 12, h = lane - s * 12;
        float acc = bout[h];
#pragma unroll 4
        for (int ig = 0; ig < 16; ++ig) {
            const float4 f4 = *(const float4*)&buf[wv][s][5][ig * 4];
            acc = fmaf(f4.x, wout[(ig * 4 + 0) * 12 + h], acc);
            acc = fmaf(f4.y, wout[(ig * 4 + 1) * 12 + h], acc);
            acc = fmaf(f4.z, wout[(ig * 4 + 2) * 12 + h], acc);
            acc = fmaf(f4.w, wout[(ig * 4 + 3) * 12 + h], acc);
        }
        outp[h * 8000 + sb + s] = acc;
    }
}

extern "C" void kernel_launch(void* const* d_in, const int* in_sizes, int n_in,
                              void* d_out, int out_size, void* d_ws, size_t ws_size,
                              hipStream_t stream) {
    const float* inputs     = (const float*)d_in[0];
    const float* node_feas  = (const float*)d_in[1];
    const int*   node_index = (const int*)  d_in[2];
    const float* w_fc3 = (const float*)d_in[3];
    const float* b_fc3 = (const float*)d_in[4];
    const float* w_fc4 = (const float*)d_in[5];
    const float* b_fc4 = (const float*)d_in[6];
    const float* w_fc5 = (const float*)d_in[7];
    const float* b_fc5 = (const float*)d_in[8];
    const float* w_nhp = (const float*)d_in[9];
    const float* b_nhp = (const float*)d_in[10];
    const float* w_q   = (const float*)d_in[11];
    const float* w_k   = (const float*)d_in[12];
    const float* w_in  = (const float*)d_in[13];
    const float* b_in  = (const float*)d_in[14];
    const float* sws   = (const float*)d_in[15];
    const float* sbs   = (const float*)d_in[16];
    const float* swn   = (const float*)d_in[17];
    const float* sbn   = (const float*)d_in[18];
    const float* tw1   = (const float*)d_in[19];
    const float* tb1   = (const float*)d_in[20];
    const float* tw2   = (const float*)d_in[21];
    const float* tb2   = (const float*)d_in[22];
    const float* wgate = (const float*)d_in[23];
    const float* bgate = (const float*)d_in[24];
    const float* wout  = (const float*)d_in[25];
    const float* bout  = (const float*)d_in[26];

    float* out  = (float*)d_out;           // (12,4,2000)        96000
    float* mid  = out + 96000;             // (4,12,2000,64)     6144000
    float* wadj = mid + 6144000;           // (2000,32)          64000

    float*  q     = (float*)d_ws;          // 128000
    float*  ek    = q     + 128000;        // 128000
    float*  nh2   = ek    + 128000;        // 128000 (includes b_nhp + b_in)
    float*  base1 = nh2   + 128000;        // 128000
    float*  xT    = base1 + 128000;        // 96000   [n][bt]
    float2* xa    = (float2*)(xT + 96000); // 96000 float2 {x, ax}
    float*  vecs  = xT + 96000 + 192000;   // 128 {s1v, n1v}
    float2* wt    = (float2*)(vecs + 128); // 16384 float2 (TCN weights)
    float4* wsg   = (float4*)(vecs + 128 + 32768);  // 4096 float4 (SAGE packed)

    k_embed<<<500, 256, 0, stream>>>(node_feas, inputs, w_fc3, b_fc3, w_fc4, b_fc4,
                                     w_fc5, b_fc5, w_q, w_k, w_nhp, b_nhp, b_in,
                                     tw1, tw2, sws, swn, wt, wsg,
                                     q, ek, nh2, xT);
    k_front<<<501, 256, 0, stream>>>(q, ek, xT, nh2, node_index,
                                     sws, sbs, swn, sbn, w_in, wsg,
                                     wadj, xa, base1, vecs);
    k_sage2<<<2000, 512, 0, stream>>>(base1, xa, vecs, node_index, wadj,
                                      wsg + 2048, sbs, sbn, mid);
    k_tcn<<<500, 256, 0, stream>>>(mid, wt, tb1, tb2,
                                   wgate, bgate, wout, bout, out);
}

// Round 8
// 114.625 us; speedup vs baseline: 3.9354x; 1.1009x over previous
//
#include <hip/hip_runtime.h>
#include <math.h>

// Sizes: N=2000, M=32, H=64, EMB=32, F=32, T=12, B=4, HOR=12, K=2, DILS=(1,2)

// ---------------- K1: node MLP -> q, ek, nh2; also xT, TCN wT, SAGE wpack ----
__global__ __launch_bounds__(256) void k_embed(
    const float* __restrict__ nf, const float* __restrict__ inputs,
    const float* __restrict__ w3, const float* __restrict__ b3,
    const float* __restrict__ w4, const float* __restrict__ b4,
    const float* __restrict__ w5, const float* __restrict__ b5,
    const float* __restrict__ wq, const float* __restrict__ wk,
    const float* __restrict__ wn, const float* __restrict__ bn,
    const float* __restrict__ b_in,
    const float* __restrict__ tw1, const float* __restrict__ tw2,
    const float* __restrict__ sws, const float* __restrict__ swn,
    float2* __restrict__ wtx, float4* __restrict__ wsg,
    float* __restrict__ qo, float* __restrict__ eko, float* __restrict__ nho,
    float* __restrict__ xT)
{
    const int tid = threadIdx.x;
    if (tid < 192) {                                   // xT transpose: 500*192 = 96000
        const int id = blockIdx.x * 192 + tid;
        const int t = id / 8000, rem = id % 8000;
        const int b = rem / 2000, n2 = rem % 2000;
        xT[n2 * 48 + b * 12 + t] = inputs[id];
    }
    if (blockIdx.x < 64) {                             // TCN weights -> [conv][i][o]{k0,k1}
        const int id = blockIdx.x * 256 + tid;
        const int c = id >> 12, rr = id & 4095;
        const int i = rr >> 6, o = rr & 63;
        const float* src = (c == 0) ? tw1 : (c == 1) ? tw2
                         : (c == 2) ? tw1 + 8192 : tw2 + 8192;
        wtx[id] = make_float2(src[o * 128 + i * 2], src[o * 128 + i * 2 + 1]);
    } else if (blockIdx.x < 80) {                      // SAGE weights -> [l][k2][h] float4
        const int id = (blockIdx.x - 64) * 256 + tid;  // 0..4095
        const int l = id >> 11, rr = id & 2047;
        const int k2 = rr >> 6, h = rr & 63;
        const float* S = sws + l * 4096;
        const float* Nn = swn + l * 4096;
        wsg[id] = make_float4(S[(2 * k2) * 64 + h],     Nn[(2 * k2) * 64 + h],
                              S[(2 * k2 + 1) * 64 + h], Nn[(2 * k2 + 1) * 64 + h]);
    }
    const int lane = tid & 63;
    const int n = blockIdx.x * 4 + (tid >> 6);

    float nfv = 0.f;
    if (lane < 32) nfv = nf[n * 32 + lane];

    float e1 = b3[lane];
#pragma unroll
    for (int f = 0; f < 32; ++f)
        e1 = fmaf(__shfl(nfv, f), w3[f * 64 + lane], e1);
    e1 = fmaxf(e1, 0.f);

    float e2 = b4[lane];
#pragma unroll
    for (int f = 0; f < 64; ++f)
        e2 = fmaf(__shfl(e1, f), w4[f * 64 + lane], e2);
    e2 = fmaxf(e2, 0.f);

    const int c = lane & 31;
    float ev = b5[c];
#pragma unroll
    for (int f = 0; f < 64; ++f)
        ev = fmaf(__shfl(e2, f), w5[f * 32 + c], ev);

    float qv = 0.f, ekv = 0.f, nhv = bn[lane] + b_in[lane];
#pragma unroll
    for (int f = 0; f < 32; ++f) {
        float e = __shfl(ev, f);
        qv  = fmaf(e, wq[f * 64 + lane], qv);
        ekv = fmaf(e, wk[f * 64 + lane], ekv);
        nhv = fmaf(e, wn[f * 64 + lane], nhv);
    }
    qo [n * 64 + lane] = qv;
    eko[n * 64 + lane] = ekv;
    nho[n * 64 + lane] = nhv;
}

// ---------------- K2: fused scores+softmax -> wadj; ax -> xa; base1 (+vecs) ----
__global__ __launch_bounds__(256) void k_front(
    const float* __restrict__ q, const float* __restrict__ ek,
    const float* __restrict__ xT, const float* __restrict__ nh2,
    const int* __restrict__ nidx,
    const float* __restrict__ sws, const float* __restrict__ sbs,
    const float* __restrict__ swn, const float* __restrict__ sbn,
    const float* __restrict__ w_in, const float4* __restrict__ wsg,
    float* __restrict__ wadj, float2* __restrict__ xa,
    float* __restrict__ base1, float* __restrict__ vecs)
{
    const int tid = threadIdx.x;
    const int lane = tid & 63, wave = tid >> 6;
    if (blockIdx.x == 500) {
        if (wave == 0) {
            const float wv = w_in[lane];
            float s1 = 0.f, n1 = 0.f;
#pragma unroll
            for (int k = 0; k < 64; ++k) {
                const float wkk = __shfl(wv, k);
                s1 = fmaf(wkk, sws[k * 64 + lane], s1);
                n1 = fmaf(wkk, swn[k * 64 + lane], n1);
            }
            vecs[lane] = s1; vecs[64 + lane] = n1;
        }
        return;
    }
    __shared__ __align__(16) float2 pair[4][64];
    const int n = blockIdx.x * 4 + wave;

    int j = 0;
    if (lane < 32) j = nidx[n * 32 + lane];
    float w;
    {
        const float4* qr = (const float4*)(q + n * 64);
        const float4* er = (const float4*)(ek + j * 64);
        float s = 0.f;
#pragma unroll
        for (int u = 0; u < 16; ++u) {
            const float4 a = qr[u], b = er[u];
            s = fmaf(a.x, b.x, s); s = fmaf(a.y, b.y, s);
            s = fmaf(a.z, b.z, s); s = fmaf(a.w, b.w, s);
        }
        s *= 0.125f;
        float mx = s;
#pragma unroll
        for (int d = 16; d >= 1; d >>= 1) mx = fmaxf(mx, __shfl_xor(mx, d));
        const float ex = expf(s - mx);
        float sum = ex;
#pragma unroll
        for (int d = 16; d >= 1; d >>= 1) sum += __shfl_xor(sum, d);
        w = ex / sum;
        if (lane < 32) wadj[n * 32 + lane] = w;
    }
    float ax = 0.f, anh = 0.f;
    const bool act = lane < 48;
#pragma unroll 8
    for (int m = 0; m < 32; ++m) {
        const int jm = __shfl(j, m);
        const float wm = __shfl(w, m);
        const float xv = act ? xT[jm * 48 + lane] : 0.f;
        ax  = fmaf(wm, xv, ax);
        anh = fmaf(wm, nh2[jm * 64 + lane], anh);
    }
    if (act) xa[n * 48 + lane] = make_float2(xT[n * 48 + lane], ax);
    pair[wave][lane] = make_float2(nh2[n * 64 + lane], anh);
    __syncthreads();

    float acc = sbs[lane] + sbn[lane];
    const float2* pw = pair[wave];
#pragma unroll
    for (int k2 = 0; k2 < 32; ++k2) {
        const float4 wv = wsg[k2 * 64 + lane];
        const float4 sv = *(const float4*)(pw + k2 * 2);
        acc = fmaf(sv.x, wv.x, acc); acc = fmaf(sv.y, wv.y, acc);
        acc = fmaf(sv.z, wv.z, acc); acc = fmaf(sv.w, wv.w, acc);
    }
    base1[n * 64 + lane] = acc;
}

// ---------------- K3: fused SAGE layer 2 (recompute h1 from scalars) -> mid ----------
__global__ __launch_bounds__(512, 8) void k_sage2(
    const float* __restrict__ base1, const float2* __restrict__ xa,
    const float* __restrict__ vecs,
    const int* __restrict__ nidx, const float* __restrict__ wadj,
    const float4* __restrict__ wsg2,
    const float* __restrict__ sbs, const float* __restrict__ sbn,
    float* __restrict__ mid)
{
    __shared__ __align__(16) float2 svp[48][64];        // {h1self, agg}, 24 KB
    const int tid = threadIdx.x, lane = tid & 63;
    const int wave = __builtin_amdgcn_readfirstlane(tid >> 6);
    const int n = blockIdx.x;
    const int bt0 = wave * 6;

    const float s1 = vecs[lane], n1 = vecs[64 + lane];
    const float bs = base1[n * 64 + lane];

    float agg[6] = {0.f, 0.f, 0.f, 0.f, 0.f, 0.f};
#pragma unroll 8
    for (int m = 0; m < 32; ++m) {
        const int j = nidx[n * 32 + m];                 // block-uniform -> s_load
        const float w = wadj[n * 32 + m];               // block-uniform -> s_load
        const float bj = base1[j * 64 + lane];
        const float4* xr = (const float4*)(xa + j * 48 + bt0);
        const float4 p0 = xr[0], p1 = xr[1], p2 = xr[2];
        float t;
        t = fmaf(p0.x, s1, fmaf(p0.y, n1, bj)); agg[0] = fmaf(w, fmaxf(t, 0.f), agg[0]);
        t = fmaf(p0.z, s1, fmaf(p0.w, n1, bj)); agg[1] = fmaf(w, fmaxf(t, 0.f), agg[1]);
        t = fmaf(p1.x, s1, fmaf(p1.y, n1, bj)); agg[2] = fmaf(w, fmaxf(t, 0.f), agg[2]);
        t = fmaf(p1.z, s1, fmaf(p1.w, n1, bj)); agg[3] = fmaf(w, fmaxf(t, 0.f), agg[3]);
        t = fmaf(p2.x, s1, fmaf(p2.y, n1, bj)); agg[4] = fmaf(w, fmaxf(t, 0.f), agg[4]);
        t = fmaf(p2.z, s1, fmaf(p2.w, n1, bj)); agg[5] = fmaf(w, fmaxf(t, 0.f), agg[5]);
    }
    {
        const float4* xs = (const float4*)(xa + n * 48 + bt0);
        const float4 q0 = xs[0], q1 = xs[1], q2 = xs[2];
        svp[bt0 + 0][lane] = make_float2(fmaxf(fmaf(q0.x, s1, fmaf(q0.y, n1, bs)), 0.f), agg[0]);
        svp[bt0 + 1][lane] = make_float2(fmaxf(fmaf(q0.z, s1, fmaf(q0.w, n1, bs)), 0.f), agg[1]);
        svp[bt0 + 2][lane] = make_float2(fmaxf(fmaf(q1.x, s1, fmaf(q1.y, n1, bs)), 0.f), agg[2]);
        svp[bt0 + 3][lane] = make_float2(fmaxf(fmaf(q1.z, s1, fmaf(q1.w, n1, bs)), 0.f), agg[3]);
        svp[bt0 + 4][lane] = make_float2(fmaxf(fmaf(q2.x, s1, fmaf(q2.y, n1, bs)), 0.f), agg[4]);
        svp[bt0 + 5][lane] = make_float2(fmaxf(fmaf(q2.z, s1, fmaf(q2.w, n1, bs)), 0.f), agg[5]);
    }
    const float b2 = sbs[64 + lane] + sbn[64 + lane];
    float acc[6] = {b2, b2, b2, b2, b2, b2};
    const float4* wp = wsg2 + lane;
    const float2* s0 = svp[bt0];
#pragma unroll
    for (int k2 = 0; k2 < 32; ++k2) {
        const float4 w4 = wp[k2 * 64];
        const float4 v0 = *(const float4*)(s0 + 0 * 64 + k2 * 2);
        const float4 v1 = *(const float4*)(s0 + 1 * 64 + k2 * 2);
        const float4 v2 = *(const float4*)(s0 + 2 * 64 + k2 * 2);
        const float4 v3 = *(const float4*)(s0 + 3 * 64 + k2 * 2);
        const float4 v4 = *(const float4*)(s0 + 4 * 64 + k2 * 2);
        const float4 v5 = *(const float4*)(s0 + 5 * 64 + k2 * 2);
        acc[0] = fmaf(v0.x, w4.x, fmaf(v0.y, w4.y, fmaf(v0.z, w4.z, fmaf(v0.w, w4.w, acc[0]))));
        acc[1] = fmaf(v1.x, w4.x, fmaf(v1.y, w4.y, fmaf(v1.z, w4.z, fmaf(v1.w, w4.w, acc[1]))));
        acc[2] = fmaf(v2.x, w4.x, fmaf(v2.y, w4.y, fmaf(v2.z, w4.z, fmaf(v2.w, w4.w, acc[2]))));
        acc[3] = fmaf(v3.x, w4.x, fmaf(v3.y, w4.y, fmaf(v3.z, w4.z, fmaf(v3.w, w4.w, acc[3]))));
        acc[4] = fmaf(v4.x, w4.x, fmaf(v4.y, w4.y, fmaf(v4.z, w4.z, fmaf(v4.w, w4.w, acc[4]))));
        acc[5] = fmaf(v5.x, w4.x, fmaf(v5.y, w4.y, fmaf(v5.z, w4.z, fmaf(v5.w, w4.w, acc[5]))));
    }
#pragma unroll
    for (int r = 0; r < 6; ++r)
        mid[((bt0 + r) * 2000 + n) * 64 + lane] = fmaxf(acc[r], 0.f);
}

// ---------------- K4: TCN cone-pruned, lane=channel, 2 seqs/wave, LDS-staged x ----
// All stage inputs go through per-wave LDS buffers read as uniform ds_read_b128
// broadcasts; x1 staged with coalesced per-lane loads (no scalar-load chains).
__global__ __launch_bounds__(256, 4) void k_tcn(
    const float* __restrict__ mid, const float2* __restrict__ wt,
    const float* __restrict__ tb1, const float* __restrict__ tb2,
    const float* __restrict__ wgate, const float* __restrict__ bgate,
    const float* __restrict__ wout, const float* __restrict__ bout,
    float* __restrict__ outp)
{
    __shared__ __align__(16) float buf[4][2][7][68];     // 15.2 KB
    const int tid = threadIdx.x, lane = tid & 63;
    const int wv = __builtin_amdgcn_readfirstlane(tid >> 6);
    const int sb = blockIdx.x * 8 + wv * 2;              // 1000 blocks * 8 seqs
    const int b = sb / 2000, n0 = sb - b * 2000;         // wave's 2 seqs share b
    const float* __restrict__ xb = mid + ((long)(b * 12) * 2000 + n0) * 64;

    // stage-0: coalesced x1 loads t=5..11 -> LDS; capture residuals t=7,9,11
    float r[2][3];
#pragma unroll
    for (int s = 0; s < 2; ++s) {
#pragma unroll
        for (int u = 0; u < 7; ++u) {
            const float v = xb[(5 + u) * 128000 + s * 64 + lane];
            buf[wv][s][u][lane] = v;
            if (u == 2) r[s][0] = v;
            if (u == 4) r[s][1] = v;
            if (u == 6) r[s][2] = v;
        }
    }
    __syncthreads();

    // ---- stage 1: y1[s][j], t=6+j (j=0..5), from x slots 0..6
    const float bs1 = tb1[lane];
    float y1[2][6];
#pragma unroll
    for (int s = 0; s < 2; ++s)
#pragma unroll
        for (int j = 0; j < 6; ++j) y1[s][j] = bs1;
#pragma unroll 4
    for (int ig = 0; ig < 16; ++ig) {
        float2 w0 = wt[(ig * 4 + 0) * 64 + lane];
        float2 w1 = wt[(ig * 4 + 1) * 64 + lane];
        float2 w2 = wt[(ig * 4 + 2) * 64 + lane];
        float2 w3 = wt[(ig * 4 + 3) * 64 + lane];
#pragma unroll
        for (int s = 0; s < 2; ++s) {
            float4 xu[7];
#pragma unroll
            for (int u = 0; u < 7; ++u)
                xu[u] = *(const float4*)&buf[wv][s][u][ig * 4];
#pragma unroll
            for (int j = 0; j < 6; ++j) {
                float acc = y1[s][j];
                acc = fmaf(w0.x, xu[j].x, acc); acc = fmaf(w0.y, xu[j + 1].x, acc);
                acc = fmaf(w1.x, xu[j].y, acc); acc = fmaf(w1.y, xu[j + 1].y, acc);
                acc = fmaf(w2.x, xu[j].z, acc); acc = fmaf(w2.y, xu[j + 1].z, acc);
                acc = fmaf(w3.x, xu[j].w, acc); acc = fmaf(w3.y, xu[j + 1].w, acc);
                y1[s][j] = acc;
            }
        }
    }
#pragma unroll
    for (int s = 0; s < 2; ++s)
#pragma unroll
        for (int j = 0; j < 6; ++j)
            buf[wv][s][j][lane] = fmaxf(y1[s][j], 0.f);
    __syncthreads();

    // ---- stage 2: a[s][v] at t=7,9,11 from y1 slots (0,1),(2,3),(4,5)
    const float bs2 = tb2[lane];
    float a[2][3];
#pragma unroll
    for (int s = 0; s < 2; ++s) { a[s][0] = bs2; a[s][1] = bs2; a[s][2] = bs2; }
#pragma unroll 4
    for (int ig = 0; ig < 16; ++ig) {
        float2 w0 = wt[4096 + (ig * 4 + 0) * 64 + lane];
        float2 w1 = wt[4096 + (ig * 4 + 1) * 64 + lane];
        float2 w2 = wt[4096 + (ig * 4 + 2) * 64 + lane];
        float2 w3 = wt[4096 + (ig * 4 + 3) * 64 + lane];
#pragma unroll
        for (int s = 0; s < 2; ++s) {
            float4 yv[6];
#pragma unroll
            for (int j = 0; j < 6; ++j)
                yv[j] = *(const float4*)&buf[wv][s][j][ig * 4];
#pragma unroll
            for (int v = 0; v < 3; ++v) {
                float acc = a[s][v];
                acc = fmaf(w0.x, yv[2*v].x, acc); acc = fmaf(w0.y, yv[2*v+1].x, acc);
                acc = fmaf(w1.x, yv[2*v].y, acc); acc = fmaf(w1.y, yv[2*v+1].y, acc);
                acc = fmaf(w2.x, yv[2*v].z, acc); acc = fmaf(w2.y, yv[2*v+1].z, acc);
                acc = fmaf(w3.x, yv[2*v].w, acc); acc = fmaf(w3.y, yv[2*v+1].w, acc);
                a[s][v] = acc;
            }
        }
    }
    float x22[2];
#pragma unroll
    for (int s = 0; s < 2; ++s) {
        const float x20 = fmaxf(fmaxf(a[s][0], 0.f) + r[s][0], 0.f);  // t=7
        const float x21 = fmaxf(fmaxf(a[s][1], 0.f) + r[s][1], 0.f);  // t=9
        x22[s]          = fmaxf(fmaxf(a[s][2], 0.f) + r[s][2], 0.f);  // t=11
        buf[wv][s][0][lane] = x20;
        buf[wv][s][1][lane] = x21;
        buf[wv][s][2][lane] = x22[s];
    }
    __syncthreads();

    // ---- stage 3: d[s][v] at t=9,11 (D=2) from x2 slots 0..2
    const float bs3 = tb1[64 + lane];
    float d[2][2];
#pragma unroll
    for (int s = 0; s < 2; ++s) { d[s][0] = bs3; d[s][1] = bs3; }
#pragma unroll 4
    for (int ig = 0; ig < 16; ++ig) {
        float2 w0 = wt[8192 + (ig * 4 + 0) * 64 + lane];
        float2 w1 = wt[8192 + (ig * 4 + 1) * 64 + lane];
        float2 w2 = wt[8192 + (ig * 4 + 2) * 64 + lane];
        float2 w3 = wt[8192 + (ig * 4 + 3) * 64 + lane];
#pragma unroll
        for (int s = 0; s < 2; ++s) {
            float4 x0 = *(const float4*)&buf[wv][s][0][ig * 4];
            float4 x1 = *(const float4*)&buf[wv][s][1][ig * 4];
            float4 x2 = *(const float4*)&buf[wv][s][2][ig * 4];
            float acc0 = d[s][0], acc1 = d[s][1];
            acc0 = fmaf(w0.x, x0.x, acc0); acc0 = fmaf(w0.y, x1.x, acc0);
            acc0 = fmaf(w1.x, x0.y, acc0); acc0 = fmaf(w1.y, x1.y, acc0);
            acc0 = fmaf(w2.x, x0.z, acc0); acc0 = fmaf(w2.y, x1.z, acc0);
            acc0 = fmaf(w3.x, x0.w, acc0); acc0 = fmaf(w3.y, x1.w, acc0);
            acc1 = fmaf(w0.x, x1.x, acc1); acc1 = fmaf(w0.y, x2.x, acc1);
            acc1 = fmaf(w1.x, x1.y, acc1); acc1 = fmaf(w1.y, x2.y, acc1);
            acc1 = fmaf(w2.x, x1.z, acc1); acc1 = fmaf(w2.y, x2.z, acc1);
            acc1 = fmaf(w3.x, x1.w, acc1); acc1 = fmaf(w3.y, x2.w, acc1);
            d[s][0] = acc0; d[s][1] = acc1;
        }
    }
#pragma unroll
    for (int s = 0; s < 2; ++s) {
        buf[wv][s][4][lane] = fmaxf(d[s][0], 0.f);   // y3@9
        buf[wv][s][5][lane] = fmaxf(d[s][1], 0.f);   // y3@11
    }
    __syncthreads();

    // ---- stage 4: f[s] at t=11 (D=2) from y3 slots 4,5
    const float bs4 = tb2[64 + lane];
    float f[2] = {bs4, bs4};
#pragma unroll 4
    for (int ig = 0; ig < 16; ++ig) {
        float2 w0 = wt[12288 + (ig * 4 + 0) * 64 + lane];
        float2 w1 = wt[12288 + (ig * 4 + 1) * 64 + lane];
        float2 w2 = wt[12288 + (ig * 4 + 2) * 64 + lane];
        float2 w3 = wt[12288 + (ig * 4 + 3) * 64 + lane];
#pragma unroll
        for (int s = 0; s < 2; ++s) {
            float4 g0 = *(const float4*)&buf[wv][s][4][ig * 4];
            float4 g1 = *(const float4*)&buf[wv][s][5][ig * 4];
            float acc = f[s];
            acc = fmaf(w0.x, g0.x, acc); acc = fmaf(w0.y, g1.x, acc);
            acc = fmaf(w1.x, g0.y, acc); acc = fmaf(w1.y, g1.y, acc);
            acc = fmaf(w2.x, g0.z, acc); acc = fmaf(w2.y, g1.z, acc);
            acc = fmaf(w3.x, g0.w, acc); acc = fmaf(w3.y, g1.w, acc);
            f[s] = acc;
        }
    }

    // ---- epilogue: gate + fuse; fo -> slot 6; 24 lanes do the 12-wide head GEMV
    const float wg = wgate[lane];
#pragma unroll
    for (int s = 0; s < 2; ++s) {
        const float ht = fmaxf(fmaxf(f[s], 0.f) + x22[s], 0.f);
        float p = ht * wg;
#pragma unroll
        for (int dd = 1; dd < 64; dd <<= 1) p += __shfl_xor(p, dd);
        const float g = 1.f / (1.f + expf(-(p + bgate[0])));
        buf[wv][s][6][lane] = g * ht + (1.f - g) * r[s][2];
    }
    __syncthreads();
    if (lane < 24) {
        const int s = lane / 12, h = lane - s * 12;
        float acc = bout[h];
#pragma unroll 4
        for (int ig = 0; ig < 16; ++ig) {
            const float4 f4 = *(const float4*)&buf[wv][s][6][ig * 4];
            acc = fmaf(f4.x, wout[(ig * 4 + 0) * 12 + h], acc);
            acc = fmaf(f4.y, wout[(ig * 4 + 1) * 12 + h], acc);
            acc = fmaf(f4.z, wout[(ig * 4 + 2) * 12 + h], acc);
            acc = fmaf(f4.w, wout[(ig * 4 + 3) * 12 + h], acc);
        }
        outp[h * 8000 + sb + s] = acc;
    }
}

extern "C" void kernel_launch(void* const* d_in, const int* in_sizes, int n_in,
                              void* d_out, int out_size, void* d_ws, size_t ws_size,
                              hipStream_t stream) {
    const float* inputs     = (const float*)d_in[0];
    const float* node_feas  = (const float*)d_in[1];
    const int*   node_index = (const int*)  d_in[2];
    const float* w_fc3 = (const float*)d_in[3];
    const float* b_fc3 = (const float*)d_in[4];
    const float* w_fc4 = (const float*)d_in[5];
    const float* b_fc4 = (const float*)d_in[6];
    const float* w_fc5 = (const float*)d_in[7];
    const float* b_fc5 = (const float*)d_in[8];
    const float* w_nhp = (const float*)d_in[9];
    const float* b_nhp = (const float*)d_in[10];
    const float* w_q   = (const float*)d_in[11];
    const float* w_k   = (const float*)d_in[12];
    const float* w_in  = (const float*)d_in[13];
    const float* b_in  = (const float*)d_in[14];
    const float* sws   = (const float*)d_in[15];
    const float* sbs   = (const float*)d_in[16];
    const float* swn   = (const float*)d_in[17];
    const float* sbn   = (const float*)d_in[18];
    const float* tw1   = (const float*)d_in[19];
    const float* tb1   = (const float*)d_in[20];
    const float* tw2   = (const float*)d_in[21];
    const float* tb2   = (const float*)d_in[22];
    const float* wgate = (const float*)d_in[23];
    const float* bgate = (const float*)d_in[24];
    const float* wout  = (const float*)d_in[25];
    const float* bout  = (const float*)d_in[26];

    float* out  = (float*)d_out;           // (12,4,2000)        96000
    float* mid  = out + 96000;             // (4,12,2000,64)     6144000
    float* wadj = mid + 6144000;           // (2000,32)          64000

    float*  q     = (float*)d_ws;          // 128000
    float*  ek    = q     + 128000;        // 128000
    float*  nh2   = ek    + 128000;        // 128000 (includes b_nhp + b_in)
    float*  base1 = nh2   + 128000;        // 128000
    float*  xT    = base1 + 128000;        // 96000   [n][bt]
    float2* xa    = (float2*)(xT + 96000); // 96000 float2 {x, ax}
    float*  vecs  = xT + 96000 + 192000;   // 128 {s1v, n1v}
    float2* wt    = (float2*)(vecs + 128); // 16384 float2 (TCN weights)
    float4* wsg   = (float4*)(vecs + 128 + 32768);  // 4096 float4 (SAGE packed)

    k_embed<<<500, 256, 0, stream>>>(node_feas, inputs, w_fc3, b_fc3, w_fc4, b_fc4,
                                     w_fc5, b_fc5, w_q, w_k, w_nhp, b_nhp, b_in,
                                     tw1, tw2, sws, swn, wt, wsg,
                                     q, ek, nh2, xT);
    k_front<<<501, 256, 0, stream>>>(q, ek, xT, nh2, node_index,
                                     sws, sbs, swn, sbn, w_in, wsg,
                                     wadj, xa, base1, vecs);
    k_sage2<<<2000, 512, 0, stream>>>(base1, xa, vecs, node_index, wadj,
                                      wsg + 2048, sbs, sbn, mid);
    k_tcn<<<1000, 256, 0, stream>>>(mid, wt, tb1, tb2,
                                    wgate, bgate, wout, bout, out);
}